// Round 6
// baseline (10840.170 us; speedup 1.0000x reference)
//
#include <hip/hip_runtime.h>

#define NN 81920
#define NE 180224
#define NB 2048
#define D 300
#define NL 5
#define KP1 320          // padded K for GEMM1 (agg planes stride)
#define NP1 640          // padded N for GEMM1 (slab stride)
#define KP2 640          // padded K for GEMM2 (= NP1)
#define NP2 320          // padded N for GEMM2 (160-multiple, only 6.7% pad)
#define FKP 320          // feature planes stride (logits K)

static constexpr float TEMP_INV = 25.0f;   // 1/0.04
static constexpr float BN_EPS_C = 1e-5f;

typedef __attribute__((ext_vector_type(8))) short short8;
typedef __attribute__((ext_vector_type(4))) float f32x4;

__device__ inline void split_bf16(float v, short& hi, short& lo) {
  unsigned u = __float_as_uint(v);
  hi = (short)(u >> 16);
  float r = v - __uint_as_float(u & 0xffff0000u);
  lo = (short)(__float_as_uint(r) >> 16);
}

// ---------------- init h = atom_emb1[x0] + atom_emb2[x1] ----------------
__global__ void k_init_h(const int* __restrict__ x, const float* __restrict__ ae1,
                         const float* __restrict__ ae2, float* __restrict__ h) {
  int i = blockIdx.x;
  int i0 = x[2 * i], i1 = x[2 * i + 1];
  const float* r1 = ae1 + (size_t)i0 * D;
  const float* r2 = ae2 + (size_t)i1 * D;
  float* ho = h + (size_t)i * D;
  for (int f = threadIdx.x; f < D; f += blockDim.x) ho[f] = r1[f] + r2[f];
}

// ---------------- CSR build ----------------
__global__ void k_count(const int* __restrict__ ei, int* __restrict__ cnt) {
  int e = blockIdx.x * blockDim.x + threadIdx.x;
  if (e < NE) atomicAdd(&cnt[ei[NE + e]], 1);
}

__global__ void k_scan(const int* __restrict__ cnt, int* __restrict__ rs) {
  __shared__ int sdata[1024];
  int t = threadIdx.x;
  int base = t * 80;                 // 1024*80 == 81920
  int s = 0;
  for (int j = 0; j < 80; ++j) s += cnt[base + j];
  sdata[t] = s;
  __syncthreads();
  for (int off = 1; off < 1024; off <<= 1) {
    int v = (t >= off) ? sdata[t - off] : 0;
    __syncthreads();
    sdata[t] += v;
    __syncthreads();
  }
  int run = sdata[t] - s;
  for (int j = 0; j < 80; ++j) { rs[base + j] = run; run += cnt[base + j]; }
  if (t == 1023) rs[NN] = run;
}

__global__ void k_bucket(const int* __restrict__ ei, const int* __restrict__ ea,
                         const int* __restrict__ rs, int* __restrict__ fill,
                         int* __restrict__ srcs, int* __restrict__ attrs) {
  int e = blockIdx.x * blockDim.x + threadIdx.x;
  if (e >= NE) return;
  int d = ei[NE + e];
  int p = rs[d] + atomicAdd(&fill[d], 1);
  srcs[p] = ei[e];
  attrs[p] = ea[2 * e] | (ea[2 * e + 1] << 8);
}

// ---------------- gather (+ fused BN-apply+ReLU of previous layer) ----------------
template <bool BN>
__global__ void k_gather(const float* __restrict__ h, const int* __restrict__ rs,
                         const int* __restrict__ srcs, const int* __restrict__ attrs,
                         const float* __restrict__ T1, const float* __restrict__ T2,
                         const float* __restrict__ scsh,
                         short* __restrict__ aggH, short* __restrict__ aggL) {
  int i = blockIdx.x;
  int j0 = rs[i], j1 = rs[i + 1];
  int t = threadIdx.x;               // 128
  int f0 = t, f1 = t + 128, f2 = t + 256;
  float sc0 = 0, sh0 = 0, sc1 = 0, sh1 = 0, sc2 = 0, sh2 = 0;
  if (BN) {
    sc0 = scsh[f0]; sh0 = scsh[D + f0];
    sc1 = scsh[f1]; sh1 = scsh[D + f1];
    if (f2 < D) { sc2 = scsh[f2]; sh2 = scsh[D + f2]; }
  }
  auto u0 = [&](float x) { return BN ? fmaxf(fmaf(x, sc0, sh0), 0.f) : x; };
  auto u1 = [&](float x) { return BN ? fmaxf(fmaf(x, sc1, sh1), 0.f) : x; };
  auto u2 = [&](float x) { return BN ? fmaxf(fmaf(x, sc2, sh2), 0.f) : x; };
  const float* hi = h + (size_t)i * D;
  float a0 = u0(hi[f0]) + T1[4 * D + f0] + T2[f0];
  float a1 = u1(hi[f1]) + T1[4 * D + f1] + T2[f1];
  float a2 = (f2 < D) ? (u2(hi[f2]) + T1[4 * D + f2] + T2[f2]) : 0.f;
  for (int j = j0; j < j1; ++j) {
    int s = srcs[j];
    int at = attrs[j];
    const float* hs = h + (size_t)s * D;
    const float* t1 = T1 + (size_t)(at & 255) * D;
    const float* t2 = T2 + (size_t)(at >> 8) * D;
    a0 += u0(hs[f0]) + t1[f0] + t2[f0];
    a1 += u1(hs[f1]) + t1[f1] + t2[f1];
    if (f2 < D) a2 += u2(hs[f2]) + t1[f2] + t2[f2];
  }
  size_t base = (size_t)i * KP1;
  short hh, ll;
  split_bf16(a0, hh, ll); aggH[base + f0] = hh; aggL[base + f0] = ll;
  split_bf16(a1, hh, ll); aggH[base + f1] = hh; aggL[base + f1] = ll;
  if (f2 < KP1) {
    split_bf16(a2, hh, ll); aggH[base + f2] = hh; aggL[base + f2] = ll;
  }
}

// ---------------- weight pre-transpose + split:  T[n][k] = W[k][n], zero-padded --------
__global__ void k_prepw(const float* __restrict__ W, short* __restrict__ TH,
                        short* __restrict__ TL, int K, int Nc, int Kp, int Np) {
  int idx = blockIdx.x * blockDim.x + threadIdx.x;
  int per = Np * Kp;
  if (idx >= NL * per) return;
  int l = idx / per, r = idx % per;
  int n = r / Kp, k = r % Kp;
  float v = (n < Nc && k < K) ? W[(size_t)l * K * Nc + (size_t)k * Nc + n] : 0.f;
  short hi, lo;
  split_bf16(v, hi, lo);
  TH[idx] = hi;
  TL[idx] = lo;
}

// ---------------- split-bf16 MFMA GEMM, tile 128x160, 4 waves (64x80/wave), no LDS ----
// MODE 0: relu(bias+C) -> split planes (GEMM1)
// MODE 1: bias+C -> fp32 Cf (col<maskN) + fused BN-stats atomics (GEMM2)
template <int MODE, int KK>
__global__ __launch_bounds__(256) void k_mfma_gemm(
    const short* __restrict__ AH, const short* __restrict__ AL,
    const short* __restrict__ BH, const short* __restrict__ BL,
    const float* __restrict__ bias, int biasN,
    short* __restrict__ CHp, short* __restrict__ CLp, int ldcp,
    float* __restrict__ Cf, int ldcf, int maskN, float* __restrict__ stats) {
  int lane = threadIdx.x & 63;
  int w = threadIdx.x >> 6;
  int m0 = blockIdx.x * 128 + (w >> 1) * 64;
  int n0 = blockIdx.y * 160 + (w & 1) * 80;
  int rl = lane & 15;
  int kg = (lane >> 4) * 8;
  f32x4 acc[4][5] = {};
  for (int k0 = 0; k0 < KK; k0 += 32) {
    int kk = k0 + kg;
    short8 aH[4], aL[4], bH[5], bL[5];
#pragma unroll
    for (int rf = 0; rf < 4; ++rf) {
      size_t off = (size_t)(m0 + rf * 16 + rl) * KK + kk;
      aH[rf] = *(const short8*)(AH + off);
      aL[rf] = *(const short8*)(AL + off);
    }
#pragma unroll
    for (int cf = 0; cf < 5; ++cf) {
      size_t off = (size_t)(n0 + cf * 16 + rl) * KK + kk;
      bH[cf] = *(const short8*)(BH + off);
      bL[cf] = *(const short8*)(BL + off);
    }
#pragma unroll
    for (int rf = 0; rf < 4; ++rf)
#pragma unroll
      for (int cf = 0; cf < 5; ++cf) {
        acc[rf][cf] = __builtin_amdgcn_mfma_f32_16x16x32_bf16(aH[rf], bH[cf], acc[rf][cf], 0, 0, 0);
        acc[rf][cf] = __builtin_amdgcn_mfma_f32_16x16x32_bf16(aH[rf], bL[cf], acc[rf][cf], 0, 0, 0);
        acc[rf][cf] = __builtin_amdgcn_mfma_f32_16x16x32_bf16(aL[rf], bH[cf], acc[rf][cf], 0, 0, 0);
      }
  }
#pragma unroll
  for (int cf = 0; cf < 5; ++cf) {
    int col = n0 + cf * 16 + rl;
    float bv = (col < biasN) ? bias[col] : 0.f;
    float s = 0.f, q = 0.f;
#pragma unroll
    for (int rf = 0; rf < 4; ++rf) {
#pragma unroll
      for (int i = 0; i < 4; ++i) {
        int row = m0 + rf * 16 + (lane >> 4) * 4 + i;
        float v = acc[rf][cf][i] + bv;
        if (MODE == 0) {
          v = fmaxf(v, 0.f);
          short hi, lo;
          split_bf16(v, hi, lo);
          CHp[(size_t)row * ldcp + col] = hi;
          CLp[(size_t)row * ldcp + col] = lo;
        } else {
          if (col < maskN) Cf[(size_t)row * ldcf + col] = v;
          s += v; q += v * v;
        }
      }
    }
    if (MODE == 1) {
      s += __shfl_xor(s, 16); s += __shfl_xor(s, 32);
      q += __shfl_xor(q, 16); q += __shfl_xor(q, 32);
      if ((lane >> 4) == 0 && col < maskN) {
        atomicAdd(&stats[col], s);
        atomicAdd(&stats[D + col], q);
      }
    }
  }
}

// ---------------- fp32 tiled GEMM (projector only) ----------------
template <bool RELU>
__global__ __launch_bounds__(256) void k_gemm(const float* __restrict__ A,
                                              const float* __restrict__ Bm,
                                              const float* __restrict__ bias,
                                              float* __restrict__ C,
                                              int M, int K, int Nc) {
  __shared__ float As[8][132];
  __shared__ float Bs[8][132];
  int tid = threadIdx.x;
  int tx = tid & 15, ty = tid >> 4;
  int m0 = blockIdx.x * 128, n0 = blockIdx.y * 128;
  float acc[8][8] = {};
  int ar = tid >> 1, akq = (tid & 1) * 4;
  int bk = tid >> 5, bn = (tid & 31) * 4;
  for (int kk = 0; kk < K; kk += 8) {
    {
      int gr = m0 + ar, gk = kk + akq;
      if (gr < M && gk + 3 < K) {
        float4 v = *(const float4*)(A + (size_t)gr * K + gk);
        As[akq + 0][ar] = v.x; As[akq + 1][ar] = v.y;
        As[akq + 2][ar] = v.z; As[akq + 3][ar] = v.w;
      } else {
#pragma unroll
        for (int u = 0; u < 4; ++u)
          As[akq + u][ar] = (gr < M && gk + u < K) ? A[(size_t)gr * K + gk + u] : 0.f;
      }
    }
    {
      int gk = kk + bk, gn = n0 + bn;
      if (gk < K && gn + 3 < Nc) {
        *(float4*)&Bs[bk][bn] = *(const float4*)(Bm + (size_t)gk * Nc + gn);
      } else {
#pragma unroll
        for (int u = 0; u < 4; ++u)
          Bs[bk][bn + u] = (gk < K && gn + u < Nc) ? Bm[(size_t)gk * Nc + gn + u] : 0.f;
      }
    }
    __syncthreads();
#pragma unroll
    for (int k = 0; k < 8; ++k) {
      float4 a0 = *(const float4*)&As[k][ty * 8];
      float4 a1 = *(const float4*)&As[k][ty * 8 + 4];
      float4 b0 = *(const float4*)&Bs[k][tx * 8];
      float4 b1 = *(const float4*)&Bs[k][tx * 8 + 4];
      float av[8] = {a0.x, a0.y, a0.z, a0.w, a1.x, a1.y, a1.z, a1.w};
      float bv[8] = {b0.x, b0.y, b0.z, b0.w, b1.x, b1.y, b1.z, b1.w};
#pragma unroll
      for (int i = 0; i < 8; ++i)
#pragma unroll
        for (int j = 0; j < 8; ++j) acc[i][j] = fmaf(av[i], bv[j], acc[i][j]);
    }
    __syncthreads();
  }
  int rbase = m0 + ty * 8, cbase = n0 + tx * 8;
#pragma unroll
  for (int i = 0; i < 8; ++i) {
    int r = rbase + i;
    if (r >= M) break;
#pragma unroll
    for (int j = 0; j < 8; ++j) {
      int c = cbase + j;
      if (c >= Nc) continue;
      float v = acc[i][j] + bias[c];
      if (RELU) v = fmaxf(v, 0.f);
      C[(size_t)r * Nc + c] = v;
    }
  }
}

// ---------------- BN finalize (stats -> scale/shift) ----------------
__global__ void k_bnfinal(const float* __restrict__ stats, const float* __restrict__ g,
                          const float* __restrict__ b, float* __restrict__ scsh) {
  int t = threadIdx.x;
  if (t >= D) return;
  float mean = stats[t] * (1.0f / NN);
  float var = stats[D + t] * (1.0f / NN) - mean * mean;
  float inv = rsqrtf(var + BN_EPS_C);
  float sc = g[t] * inv;
  scsh[t] = sc;
  scsh[D + t] = b[t] - mean * sc;
}

// ---------------- pooling (batch sorted) + fused last-layer BN (affine, no relu) ------
__global__ void k_gstart(const int* __restrict__ batch, int* __restrict__ gs) {
  int i = blockIdx.x * blockDim.x + threadIdx.x;
  if (i >= NN) return;
  int b = batch[i];
  int bp = (i == 0) ? -1 : batch[i - 1];
  for (int q = bp + 1; q <= b; ++q) gs[q] = i;
  if (i == NN - 1)
    for (int q = b + 1; q <= NB; ++q) gs[q] = NN;
}

__global__ void k_poolseg(const float* __restrict__ h, const int* __restrict__ gs,
                          const float* __restrict__ scsh, float* __restrict__ g) {
  int b = blockIdx.x;
  int j0 = gs[b], j1 = gs[b + 1];
  int t = threadIdx.x;               // 128
  float s0 = 0, s1 = 0, s2 = 0;
  int c2 = t + 256;
  for (int j = j0; j < j1; ++j) {
    const float* row = h + (size_t)j * D;
    s0 += row[t];
    s1 += row[t + 128];
    if (c2 < D) s2 += row[c2];
  }
  bool nz = j1 > j0;
  float invc = nz ? 1.f / (float)(j1 - j0) : 0.f;
  float* go = g + (size_t)b * D;
  go[t] = nz ? fmaf(s0 * invc, scsh[t], scsh[D + t]) : 0.f;
  go[t + 128] = nz ? fmaf(s1 * invc, scsh[t + 128], scsh[D + t + 128]) : 0.f;
  if (c2 < D) go[c2] = nz ? fmaf(s2 * invc, scsh[c2], scsh[D + c2]) : 0.f;
}

// ---------------- L2 normalize -> split feature planes [4096, FKP] ----------------
__global__ void k_norm(const float* __restrict__ pin, short* __restrict__ FH,
                       short* __restrict__ FL, int ro) {
  int b = blockIdx.x;
  int t = threadIdx.x;               // 64
  const float* row = pin + (size_t)b * D;
  float q = 0;
  for (int c = t; c < D; c += 64) { float v = row[c]; q += v * v; }
#pragma unroll
  for (int off = 32; off > 0; off >>= 1) q += __shfl_down(q, off);
  q = __shfl(q, 0);
  float inv = 1.f / fmaxf(sqrtf(q), 1e-12f);
  size_t base = (size_t)(ro + b) * FKP;
  for (int c = t; c < FKP; c += 64) {
    float v = (c < D) ? row[c] * inv : 0.f;
    short hi, lo;
    split_bf16(v, hi, lo);
    FH[base + c] = hi;
    FL[base + c] = lo;
  }
}

// ---------------- MFMA sim = F F^T fused with NT-Xent logits layout ----------------
__global__ __launch_bounds__(256) void k_logits_mfma(const short* __restrict__ FH,
                                                     const short* __restrict__ FL,
                                                     float* __restrict__ out) {
  int lane = threadIdx.x & 63;
  int w = threadIdx.x >> 6;
  int m0 = blockIdx.x * 128 + (w >> 1) * 64;
  int n0 = blockIdx.y * 128 + (w & 1) * 64;
  int rl = lane & 15;
  int kg = (lane >> 4) * 8;
  f32x4 acc[4][4] = {};
  for (int k0 = 0; k0 < FKP; k0 += 32) {
    int kk = k0 + kg;
    short8 aH[4], aL[4], bH[4], bL[4];
#pragma unroll
    for (int rf = 0; rf < 4; ++rf) {
      size_t off = (size_t)(m0 + rf * 16 + rl) * FKP + kk;
      aH[rf] = *(const short8*)(FH + off);
      aL[rf] = *(const short8*)(FL + off);
    }
#pragma unroll
    for (int cf = 0; cf < 4; ++cf) {
      size_t off = (size_t)(n0 + cf * 16 + rl) * FKP + kk;
      bH[cf] = *(const short8*)(FH + off);
      bL[cf] = *(const short8*)(FL + off);
    }
#pragma unroll
    for (int rf = 0; rf < 4; ++rf)
#pragma unroll
      for (int cf = 0; cf < 4; ++cf) {
        acc[rf][cf] = __builtin_amdgcn_mfma_f32_16x16x32_bf16(aH[rf], bH[cf], acc[rf][cf], 0, 0, 0);
        acc[rf][cf] = __builtin_amdgcn_mfma_f32_16x16x32_bf16(aH[rf], bL[cf], acc[rf][cf], 0, 0, 0);
        acc[rf][cf] = __builtin_amdgcn_mfma_f32_16x16x32_bf16(aL[rf], bH[cf], acc[rf][cf], 0, 0, 0);
      }
  }
#pragma unroll
  for (int rf = 0; rf < 4; ++rf) {
#pragma unroll
    for (int cf = 0; cf < 4; ++cf) {
      int c = n0 + cf * 16 + rl;
#pragma unroll
      for (int i = 0; i < 4; ++i) {
        int r = m0 + rf * 16 + (lane >> 4) * 4 + i;
        if (c == r) continue;
        float v = acc[rf][cf][i] * TEMP_INV;
        int posj = (r + NB) & 4095;
        int slot = (c == posj) ? 0 : (1 + c - (c > r) - (c > posj));
        out[(size_t)r * 4095 + slot] = v;
      }
    }
  }
}

// ---------------- host ----------------
extern "C" void kernel_launch(void* const* d_in, const int* in_sizes, int n_in,
                              void* d_out, int out_size, void* d_ws, size_t ws_size,
                              hipStream_t stream) {
  const int* xs[2] = {(const int*)d_in[0], (const int*)d_in[4]};
  const int* eis[2] = {(const int*)d_in[1], (const int*)d_in[5]};
  const int* eas[2] = {(const int*)d_in[2], (const int*)d_in[6]};
  const int* bts[2] = {(const int*)d_in[3], (const int*)d_in[7]};
  const float* ae1 = (const float*)d_in[8];
  const float* ae2 = (const float*)d_in[9];
  const float* ee1 = (const float*)d_in[10];
  const float* ee2 = (const float*)d_in[11];
  const float* W1 = (const float*)d_in[12];
  const float* b1 = (const float*)d_in[13];
  const float* W2 = (const float*)d_in[14];
  const float* b2 = (const float*)d_in[15];
  const float* bng = (const float*)d_in[16];
  const float* bnb = (const float*)d_in[17];
  const float* pW1 = (const float*)d_in[18];
  const float* pb1 = (const float*)d_in[19];
  const float* pW2 = (const float*)d_in[20];
  const float* pb2 = (const float*)d_in[21];

  char* p = (char*)d_ws;
  auto alloc = [&](size_t bytes) -> void* {
    void* q = (void*)p;
    p += (bytes + 255) & ~(size_t)255;
    return q;
  };
  float* h    = (float*)alloc((size_t)NN * D * 4);          // 98.3 MB
  short* aggH = (short*)alloc((size_t)NN * KP1 * 2);        // 52.4 MB
  short* aggL = (short*)alloc((size_t)NN * KP1 * 2);        // 52.4 MB
  short* w1tH = (short*)alloc((size_t)NL * NP1 * KP1 * 2);
  short* w1tL = (short*)alloc((size_t)NL * NP1 * KP1 * 2);
  short* w2tH = (short*)alloc((size_t)NL * NP2 * KP2 * 2);
  short* w2tL = (short*)alloc((size_t)NL * NP2 * KP2 * 2);
  short* featH = (short*)alloc((size_t)2 * NB * FKP * 2);
  short* featL = (short*)alloc((size_t)2 * NB * FKP * 2);
  int* cnt    = (int*)alloc((size_t)NN * 4);
  int* rs     = (int*)alloc((size_t)(NN + 1) * 4);
  int* srcs   = (int*)alloc((size_t)NE * 4);
  int* attrs  = (int*)alloc((size_t)NE * 4);
  float* stats = (float*)alloc(600 * 4);
  float* scsh  = (float*)alloc(600 * 4);
  int* gstart  = (int*)alloc((size_t)(NB + 1) * 4);
  float* pg   = (float*)alloc((size_t)NB * D * 4);
  float* pt   = (float*)alloc((size_t)NB * D * 4);

  // slab gets ALL remaining workspace -> adaptive chunk size (constant across calls)
  size_t used = (size_t)(p - (char*)d_ws);
  size_t rem = (ws_size > used + (1u << 20)) ? ws_size - used - (1u << 20) : 0;
  long chRows = (long)(rem / ((size_t)NP1 * 4));   // bytes per slab row (hi+lo bf16)
  int CHr = (int)(chRows & ~127L);
  if (CHr < 128) CHr = 128;
  if (CHr > NN) CHr = NN;
  short* slabH = (short*)alloc((size_t)CHr * NP1 * 2);
  short* slabL = (short*)alloc((size_t)CHr * NP1 * 2);

  k_prepw<<<(NL * NP1 * KP1 + 255) / 256, 256, 0, stream>>>(W1, w1tH, w1tL, 300, 600, KP1, NP1);
  k_prepw<<<(NL * NP2 * KP2 + 255) / 256, 256, 0, stream>>>(W2, w2tH, w2tL, 600, 300, KP2, NP2);

  for (int v = 0; v < 2; ++v) {
    k_init_h<<<NN, 128, 0, stream>>>(xs[v], ae1, ae2, h);
    hipMemsetAsync(cnt, 0, (size_t)NN * 4, stream);
    k_count<<<(NE + 255) / 256, 256, 0, stream>>>(eis[v], cnt);
    k_scan<<<1, 1024, 0, stream>>>(cnt, rs);
    hipMemsetAsync(cnt, 0, (size_t)NN * 4, stream);
    k_bucket<<<(NE + 255) / 256, 256, 0, stream>>>(eis[v], eas[v], rs, cnt, srcs, attrs);

    for (int l = 0; l < NL; ++l) {
      if (l == 0)
        k_gather<false><<<NN, 128, 0, stream>>>(h, rs, srcs, attrs, ee1 + (size_t)l * 6 * D,
                                                ee2 + (size_t)l * 3 * D, nullptr, aggH, aggL);
      else
        k_gather<true><<<NN, 128, 0, stream>>>(h, rs, srcs, attrs, ee1 + (size_t)l * 6 * D,
                                               ee2 + (size_t)l * 3 * D, scsh, aggH, aggL);
      hipMemsetAsync(stats, 0, 600 * 4, stream);
      for (int c0 = 0; c0 < NN; c0 += CHr) {
        int rows = (NN - c0 < CHr) ? (NN - c0) : CHr;
        k_mfma_gemm<0, KP1><<<dim3(rows / 128, NP1 / 160), 256, 0, stream>>>(
            aggH + (size_t)c0 * KP1, aggL + (size_t)c0 * KP1,
            w1tH + (size_t)l * NP1 * KP1, w1tL + (size_t)l * NP1 * KP1,
            b1 + (size_t)l * 600, 600, slabH, slabL, NP1, nullptr, 0, 0, nullptr);
        k_mfma_gemm<1, KP2><<<dim3(rows / 128, NP2 / 160), 256, 0, stream>>>(
            slabH, slabL,
            w2tH + (size_t)l * NP2 * KP2, w2tL + (size_t)l * NP2 * KP2,
            b2 + (size_t)l * 300, 300, nullptr, nullptr, 0,
            h + (size_t)c0 * D, D, 300, stats);
      }
      k_bnfinal<<<1, 320, 0, stream>>>(stats, bng + (size_t)l * D, bnb + (size_t)l * D, scsh);
    }

    k_gstart<<<(NN + 255) / 256, 256, 0, stream>>>(bts[v], gstart);
    k_poolseg<<<NB, 128, 0, stream>>>(h, gstart, scsh, pg);
    k_gemm<true><<<dim3(NB / 128, (D + 127) / 128), 256, 0, stream>>>(pg, pW1, pb1, pt, NB, D, D);
    k_gemm<false><<<dim3(NB / 128, (D + 127) / 128), 256, 0, stream>>>(pt, pW2, pb2, pg, NB, D, D);
    k_norm<<<NB, 64, 0, stream>>>(pg, featH, featL, v * NB);
  }

  k_logits_mfma<<<dim3(4096 / 128, 4096 / 128), 256, 0, stream>>>(featH, featL, (float*)d_out);
  hipMemsetAsync((float*)d_out + (size_t)4096 * 4095, 0, (size_t)4096 * 4, stream);
}

// Round 7
// 8838.014 us; speedup vs baseline: 1.2265x; 1.2265x over previous
//
#include <hip/hip_runtime.h>

#define NN 81920
#define NE 180224
#define NB 2048
#define D 300
#define NL 5
#define KP1 320          // padded K for GEMM1 (agg planes stride)
#define NP1 640          // padded N for GEMM1 (W1T rows)
#define KP2 608          // padded K for GEMM2 (19 x 32)
#define NP2 320          // padded N for GEMM2
#define FKP 320          // feature planes stride (logits K)
#define LSTR 616         // LDS intermediate row stride (elems); 616*2B = 77*16B

static constexpr float TEMP_INV = 25.0f;   // 1/0.04
static constexpr float BN_EPS_C = 1e-5f;

typedef __attribute__((ext_vector_type(8))) short short8;
typedef __attribute__((ext_vector_type(4))) float f32x4;

__device__ inline void split_bf16(float v, short& hi, short& lo) {
  unsigned u = __float_as_uint(v);
  hi = (short)(u >> 16);
  float r = v - __uint_as_float(u & 0xffff0000u);
  lo = (short)(__float_as_uint(r) >> 16);
}

// ---------------- init h = atom_emb1[x0] + atom_emb2[x1] ----------------
__global__ void k_init_h(const int* __restrict__ x, const float* __restrict__ ae1,
                         const float* __restrict__ ae2, float* __restrict__ h) {
  int i = blockIdx.x;
  int i0 = x[2 * i], i1 = x[2 * i + 1];
  const float* r1 = ae1 + (size_t)i0 * D;
  const float* r2 = ae2 + (size_t)i1 * D;
  float* ho = h + (size_t)i * D;
  for (int f = threadIdx.x; f < D; f += blockDim.x) ho[f] = r1[f] + r2[f];
}

// ---------------- CSR build ----------------
__global__ void k_count(const int* __restrict__ ei, int* __restrict__ cnt) {
  int e = blockIdx.x * blockDim.x + threadIdx.x;
  if (e < NE) atomicAdd(&cnt[ei[NE + e]], 1);
}

__global__ void k_scan(const int* __restrict__ cnt, int* __restrict__ rs) {
  __shared__ int sdata[1024];
  int t = threadIdx.x;
  int base = t * 80;                 // 1024*80 == 81920
  int s = 0;
  for (int j = 0; j < 80; ++j) s += cnt[base + j];
  sdata[t] = s;
  __syncthreads();
  for (int off = 1; off < 1024; off <<= 1) {
    int v = (t >= off) ? sdata[t - off] : 0;
    __syncthreads();
    sdata[t] += v;
    __syncthreads();
  }
  int run = sdata[t] - s;
  for (int j = 0; j < 80; ++j) { rs[base + j] = run; run += cnt[base + j]; }
  if (t == 1023) rs[NN] = run;
}

__global__ void k_bucket(const int* __restrict__ ei, const int* __restrict__ ea,
                         const int* __restrict__ rs, int* __restrict__ fill,
                         int* __restrict__ srcs, int* __restrict__ attrs) {
  int e = blockIdx.x * blockDim.x + threadIdx.x;
  if (e >= NE) return;
  int d = ei[NE + e];
  int p = rs[d] + atomicAdd(&fill[d], 1);
  srcs[p] = ei[e];
  attrs[p] = ea[2 * e] | (ea[2 * e + 1] << 8);
}

// ---------------- gather (+ fused BN-apply+ReLU of previous layer) ----------------
template <bool BN>
__global__ void k_gather(const float* __restrict__ h, const int* __restrict__ rs,
                         const int* __restrict__ srcs, const int* __restrict__ attrs,
                         const float* __restrict__ T1, const float* __restrict__ T2,
                         const float* __restrict__ scsh,
                         short* __restrict__ aggH, short* __restrict__ aggL) {
  int i = blockIdx.x;
  int j0 = rs[i], j1 = rs[i + 1];
  int t = threadIdx.x;               // 128
  int f0 = t, f1 = t + 128, f2 = t + 256;
  float sc0 = 0, sh0 = 0, sc1 = 0, sh1 = 0, sc2 = 0, sh2 = 0;
  if (BN) {
    sc0 = scsh[f0]; sh0 = scsh[D + f0];
    sc1 = scsh[f1]; sh1 = scsh[D + f1];
    if (f2 < D) { sc2 = scsh[f2]; sh2 = scsh[D + f2]; }
  }
  auto u0 = [&](float x) { return BN ? fmaxf(fmaf(x, sc0, sh0), 0.f) : x; };
  auto u1 = [&](float x) { return BN ? fmaxf(fmaf(x, sc1, sh1), 0.f) : x; };
  auto u2 = [&](float x) { return BN ? fmaxf(fmaf(x, sc2, sh2), 0.f) : x; };
  const float* hi = h + (size_t)i * D;
  float a0 = u0(hi[f0]) + T1[4 * D + f0] + T2[f0];
  float a1 = u1(hi[f1]) + T1[4 * D + f1] + T2[f1];
  float a2 = (f2 < D) ? (u2(hi[f2]) + T1[4 * D + f2] + T2[f2]) : 0.f;
  for (int j = j0; j < j1; ++j) {
    int s = srcs[j];
    int at = attrs[j];
    const float* hs = h + (size_t)s * D;
    const float* t1 = T1 + (size_t)(at & 255) * D;
    const float* t2 = T2 + (size_t)(at >> 8) * D;
    a0 += u0(hs[f0]) + t1[f0] + t2[f0];
    a1 += u1(hs[f1]) + t1[f1] + t2[f1];
    if (f2 < D) a2 += u2(hs[f2]) + t1[f2] + t2[f2];
  }
  size_t base = (size_t)i * KP1;
  short hh, ll;
  split_bf16(a0, hh, ll); aggH[base + f0] = hh; aggL[base + f0] = ll;
  split_bf16(a1, hh, ll); aggH[base + f1] = hh; aggL[base + f1] = ll;
  if (f2 < KP1) {
    split_bf16(a2, hh, ll); aggH[base + f2] = hh; aggL[base + f2] = ll;
  }
}

// ---------------- weight pre-transpose + split:  T[n][k] = W[k][n], zero-padded --------
__global__ void k_prepw(const float* __restrict__ W, short* __restrict__ TH,
                        short* __restrict__ TL, int K, int Nc, int Kp, int Np) {
  int idx = blockIdx.x * blockDim.x + threadIdx.x;
  int per = Np * Kp;
  if (idx >= NL * per) return;
  int l = idx / per, r = idx % per;
  int n = r / Kp, k = r % Kp;
  float v = (n < Nc && k < K) ? W[(size_t)l * K * Nc + (size_t)k * Nc + n] : 0.f;
  short hi, lo;
  split_bf16(v, hi, lo);
  TH[idx] = hi;
  TL[idx] = lo;
}

// ---------------- fused GIN MLP: h = b2 + relu(agg@W1 + b1)@W2, + BN stats ----------
// Block: 4 waves, 16 rows. GEMM1 wave -> 160 cols of the 640-intermediate; LDS
// holds split planes [16][616-stride]; GEMM2 wave -> 80 output cols, K=608.
__global__ __launch_bounds__(256, 2) void k_mlp(
    const short* __restrict__ AH, const short* __restrict__ AL,
    const short* __restrict__ B1H, const short* __restrict__ B1L,
    const short* __restrict__ B2H, const short* __restrict__ B2L,
    const float* __restrict__ bias1, const float* __restrict__ bias2,
    float* __restrict__ hout, float* __restrict__ stats) {
  __shared__ __align__(16) short iH[16][LSTR];
  __shared__ __align__(16) short iL[16][LSTR];
  int lane = threadIdx.x & 63;
  int w = threadIdx.x >> 6;
  int r0 = blockIdx.x * 16;
  int rl = lane & 15;
  int g = lane >> 4;
  int kg = g * 8;
  // ---- GEMM1 ----
  {
    f32x4 acc[10] = {};
    for (int k0 = 0; k0 < KP1; k0 += 32) {
      int kk = k0 + kg;
      short8 aH = *(const short8*)(AH + (size_t)(r0 + rl) * KP1 + kk);
      short8 aL = *(const short8*)(AL + (size_t)(r0 + rl) * KP1 + kk);
#pragma unroll
      for (int cf = 0; cf < 10; ++cf) {
        size_t off = (size_t)(w * 160 + cf * 16 + rl) * KP1 + kk;
        short8 bH = *(const short8*)(B1H + off);
        short8 bL = *(const short8*)(B1L + off);
        acc[cf] = __builtin_amdgcn_mfma_f32_16x16x32_bf16(aH, bH, acc[cf], 0, 0, 0);
        acc[cf] = __builtin_amdgcn_mfma_f32_16x16x32_bf16(aH, bL, acc[cf], 0, 0, 0);
        acc[cf] = __builtin_amdgcn_mfma_f32_16x16x32_bf16(aL, bH, acc[cf], 0, 0, 0);
      }
    }
#pragma unroll
    for (int cf = 0; cf < 10; ++cf) {
      int col = w * 160 + cf * 16 + rl;
      float bv = (col < 600) ? bias1[col] : 0.f;
#pragma unroll
      for (int i = 0; i < 4; ++i) {
        int row = g * 4 + i;
        float v = fmaxf(acc[cf][i] + bv, 0.f);
        short hi, lo;
        split_bf16(v, hi, lo);
        if (col < KP2) { iH[row][col] = hi; iL[row][col] = lo; }
      }
    }
  }
  __syncthreads();
  // ---- GEMM2 ----
  f32x4 a2[5] = {};
  for (int k0 = 0; k0 < KP2; k0 += 32) {
    int kk = k0 + kg;
    short8 xH = *(const short8*)&iH[rl][kk];
    short8 xL = *(const short8*)&iL[rl][kk];
#pragma unroll
    for (int cf = 0; cf < 5; ++cf) {
      size_t off = (size_t)(w * 80 + cf * 16 + rl) * KP2 + kk;
      short8 bH = *(const short8*)(B2H + off);
      short8 bL = *(const short8*)(B2L + off);
      a2[cf] = __builtin_amdgcn_mfma_f32_16x16x32_bf16(xH, bH, a2[cf], 0, 0, 0);
      a2[cf] = __builtin_amdgcn_mfma_f32_16x16x32_bf16(xH, bL, a2[cf], 0, 0, 0);
      a2[cf] = __builtin_amdgcn_mfma_f32_16x16x32_bf16(xL, bH, a2[cf], 0, 0, 0);
    }
  }
#pragma unroll
  for (int cf = 0; cf < 5; ++cf) {
    int col = w * 80 + cf * 16 + rl;
    float bv = (col < D) ? bias2[col] : 0.f;
    float s = 0.f, q = 0.f;
#pragma unroll
    for (int i = 0; i < 4; ++i) {
      int row = g * 4 + i;
      float v = a2[cf][i] + bv;
      if (col < D) hout[(size_t)(r0 + row) * D + col] = v;
      s += v; q += v * v;
    }
    s += __shfl_xor(s, 16); s += __shfl_xor(s, 32);
    q += __shfl_xor(q, 16); q += __shfl_xor(q, 32);
    if (g == 0 && col < D) {
      atomicAdd(&stats[col], s);
      atomicAdd(&stats[D + col], q);
    }
  }
}

// ---------------- fp32 tiled GEMM (projector only) ----------------
template <bool RELU>
__global__ __launch_bounds__(256) void k_gemm(const float* __restrict__ A,
                                              const float* __restrict__ Bm,
                                              const float* __restrict__ bias,
                                              float* __restrict__ C,
                                              int M, int K, int Nc) {
  __shared__ float As[8][132];
  __shared__ float Bs[8][132];
  int tid = threadIdx.x;
  int tx = tid & 15, ty = tid >> 4;
  int m0 = blockIdx.x * 128, n0 = blockIdx.y * 128;
  float acc[8][8] = {};
  int ar = tid >> 1, akq = (tid & 1) * 4;
  int bk = tid >> 5, bn = (tid & 31) * 4;
  for (int kk = 0; kk < K; kk += 8) {
    {
      int gr = m0 + ar, gk = kk + akq;
      if (gr < M && gk + 3 < K) {
        float4 v = *(const float4*)(A + (size_t)gr * K + gk);
        As[akq + 0][ar] = v.x; As[akq + 1][ar] = v.y;
        As[akq + 2][ar] = v.z; As[akq + 3][ar] = v.w;
      } else {
#pragma unroll
        for (int u = 0; u < 4; ++u)
          As[akq + u][ar] = (gr < M && gk + u < K) ? A[(size_t)gr * K + gk + u] : 0.f;
      }
    }
    {
      int gk = kk + bk, gn = n0 + bn;
      if (gk < K && gn + 3 < Nc) {
        *(float4*)&Bs[bk][bn] = *(const float4*)(Bm + (size_t)gk * Nc + gn);
      } else {
#pragma unroll
        for (int u = 0; u < 4; ++u)
          Bs[bk][bn + u] = (gk < K && gn + u < Nc) ? Bm[(size_t)gk * Nc + gn + u] : 0.f;
      }
    }
    __syncthreads();
#pragma unroll
    for (int k = 0; k < 8; ++k) {
      float4 a0 = *(const float4*)&As[k][ty * 8];
      float4 a1 = *(const float4*)&As[k][ty * 8 + 4];
      float4 b0 = *(const float4*)&Bs[k][tx * 8];
      float4 b1 = *(const float4*)&Bs[k][tx * 8 + 4];
      float av[8] = {a0.x, a0.y, a0.z, a0.w, a1.x, a1.y, a1.z, a1.w};
      float bv[8] = {b0.x, b0.y, b0.z, b0.w, b1.x, b1.y, b1.z, b1.w};
#pragma unroll
      for (int i = 0; i < 8; ++i)
#pragma unroll
        for (int j = 0; j < 8; ++j) acc[i][j] = fmaf(av[i], bv[j], acc[i][j]);
    }
    __syncthreads();
  }
  int rbase = m0 + ty * 8, cbase = n0 + tx * 8;
#pragma unroll
  for (int i = 0; i < 8; ++i) {
    int r = rbase + i;
    if (r >= M) break;
#pragma unroll
    for (int j = 0; j < 8; ++j) {
      int c = cbase + j;
      if (c >= Nc) continue;
      float v = acc[i][j] + bias[c];
      if (RELU) v = fmaxf(v, 0.f);
      C[(size_t)r * Nc + c] = v;
    }
  }
}

// ---------------- BN finalize (stats -> scale/shift) ----------------
__global__ void k_bnfinal(const float* __restrict__ stats, const float* __restrict__ g,
                          const float* __restrict__ b, float* __restrict__ scsh) {
  int t = threadIdx.x;
  if (t >= D) return;
  float mean = stats[t] * (1.0f / NN);
  float var = stats[D + t] * (1.0f / NN) - mean * mean;
  float inv = rsqrtf(var + BN_EPS_C);
  float sc = g[t] * inv;
  scsh[t] = sc;
  scsh[D + t] = b[t] - mean * sc;
}

// ---------------- pooling (batch sorted) + fused last-layer BN (affine, no relu) ------
__global__ void k_gstart(const int* __restrict__ batch, int* __restrict__ gs) {
  int i = blockIdx.x * blockDim.x + threadIdx.x;
  if (i >= NN) return;
  int b = batch[i];
  int bp = (i == 0) ? -1 : batch[i - 1];
  for (int q = bp + 1; q <= b; ++q) gs[q] = i;
  if (i == NN - 1)
    for (int q = b + 1; q <= NB; ++q) gs[q] = NN;
}

__global__ void k_poolseg(const float* __restrict__ h, const int* __restrict__ gs,
                          const float* __restrict__ scsh, float* __restrict__ g) {
  int b = blockIdx.x;
  int j0 = gs[b], j1 = gs[b + 1];
  int t = threadIdx.x;               // 128
  float s0 = 0, s1 = 0, s2 = 0;
  int c2 = t + 256;
  for (int j = j0; j < j1; ++j) {
    const float* row = h + (size_t)j * D;
    s0 += row[t];
    s1 += row[t + 128];
    if (c2 < D) s2 += row[c2];
  }
  bool nz = j1 > j0;
  float invc = nz ? 1.f / (float)(j1 - j0) : 0.f;
  float* go = g + (size_t)b * D;
  go[t] = nz ? fmaf(s0 * invc, scsh[t], scsh[D + t]) : 0.f;
  go[t + 128] = nz ? fmaf(s1 * invc, scsh[t + 128], scsh[D + t + 128]) : 0.f;
  if (c2 < D) go[c2] = nz ? fmaf(s2 * invc, scsh[c2], scsh[D + c2]) : 0.f;
}

// ---------------- L2 normalize -> split feature planes [4096, FKP] ----------------
__global__ void k_norm(const float* __restrict__ pin, short* __restrict__ FH,
                       short* __restrict__ FL, int ro) {
  int b = blockIdx.x;
  int t = threadIdx.x;               // 64
  const float* row = pin + (size_t)b * D;
  float q = 0;
  for (int c = t; c < D; c += 64) { float v = row[c]; q += v * v; }
#pragma unroll
  for (int off = 32; off > 0; off >>= 1) q += __shfl_down(q, off);
  q = __shfl(q, 0);
  float inv = 1.f / fmaxf(sqrtf(q), 1e-12f);
  size_t base = (size_t)(ro + b) * FKP;
  for (int c = t; c < FKP; c += 64) {
    float v = (c < D) ? row[c] * inv : 0.f;
    short hi, lo;
    split_bf16(v, hi, lo);
    FH[base + c] = hi;
    FL[base + c] = lo;
  }
}

// ---------------- MFMA sim = F F^T fused with NT-Xent logits layout ----------------
__global__ __launch_bounds__(256) void k_logits_mfma(const short* __restrict__ FH,
                                                     const short* __restrict__ FL,
                                                     float* __restrict__ out) {
  int lane = threadIdx.x & 63;
  int w = threadIdx.x >> 6;
  int m0 = blockIdx.x * 128 + (w >> 1) * 64;
  int n0 = blockIdx.y * 128 + (w & 1) * 64;
  int rl = lane & 15;
  int kg = (lane >> 4) * 8;
  f32x4 acc[4][4] = {};
  for (int k0 = 0; k0 < FKP; k0 += 32) {
    int kk = k0 + kg;
    short8 aH[4], aL[4], bH[4], bL[4];
#pragma unroll
    for (int rf = 0; rf < 4; ++rf) {
      size_t off = (size_t)(m0 + rf * 16 + rl) * FKP + kk;
      aH[rf] = *(const short8*)(FH + off);
      aL[rf] = *(const short8*)(FL + off);
    }
#pragma unroll
    for (int cf = 0; cf < 4; ++cf) {
      size_t off = (size_t)(n0 + cf * 16 + rl) * FKP + kk;
      bH[cf] = *(const short8*)(FH + off);
      bL[cf] = *(const short8*)(FL + off);
    }
#pragma unroll
    for (int rf = 0; rf < 4; ++rf)
#pragma unroll
      for (int cf = 0; cf < 4; ++cf) {
        acc[rf][cf] = __builtin_amdgcn_mfma_f32_16x16x32_bf16(aH[rf], bH[cf], acc[rf][cf], 0, 0, 0);
        acc[rf][cf] = __builtin_amdgcn_mfma_f32_16x16x32_bf16(aH[rf], bL[cf], acc[rf][cf], 0, 0, 0);
        acc[rf][cf] = __builtin_amdgcn_mfma_f32_16x16x32_bf16(aL[rf], bH[cf], acc[rf][cf], 0, 0, 0);
      }
  }
#pragma unroll
  for (int rf = 0; rf < 4; ++rf) {
#pragma unroll
    for (int cf = 0; cf < 4; ++cf) {
      int c = n0 + cf * 16 + rl;
#pragma unroll
      for (int i = 0; i < 4; ++i) {
        int r = m0 + rf * 16 + (lane >> 4) * 4 + i;
        if (c == r) continue;
        float v = acc[rf][cf][i] * TEMP_INV;
        int posj = (r + NB) & 4095;
        int slot = (c == posj) ? 0 : (1 + c - (c > r) - (c > posj));
        out[(size_t)r * 4095 + slot] = v;
      }
    }
  }
}

// ---------------- host ----------------
extern "C" void kernel_launch(void* const* d_in, const int* in_sizes, int n_in,
                              void* d_out, int out_size, void* d_ws, size_t ws_size,
                              hipStream_t stream) {
  const int* xs[2] = {(const int*)d_in[0], (const int*)d_in[4]};
  const int* eis[2] = {(const int*)d_in[1], (const int*)d_in[5]};
  const int* eas[2] = {(const int*)d_in[2], (const int*)d_in[6]};
  const int* bts[2] = {(const int*)d_in[3], (const int*)d_in[7]};
  const float* ae1 = (const float*)d_in[8];
  const float* ae2 = (const float*)d_in[9];
  const float* ee1 = (const float*)d_in[10];
  const float* ee2 = (const float*)d_in[11];
  const float* W1 = (const float*)d_in[12];
  const float* b1 = (const float*)d_in[13];
  const float* W2 = (const float*)d_in[14];
  const float* b2 = (const float*)d_in[15];
  const float* bng = (const float*)d_in[16];
  const float* bnb = (const float*)d_in[17];
  const float* pW1 = (const float*)d_in[18];
  const float* pb1 = (const float*)d_in[19];
  const float* pW2 = (const float*)d_in[20];
  const float* pb2 = (const float*)d_in[21];

  char* p = (char*)d_ws;
  auto alloc = [&](size_t bytes) -> void* {
    void* q = (void*)p;
    p += (bytes + 255) & ~(size_t)255;
    return q;
  };
  float* h    = (float*)alloc((size_t)NN * D * 4);          // 98.3 MB
  short* aggH = (short*)alloc((size_t)NN * KP1 * 2);        // 52.4 MB
  short* aggL = (short*)alloc((size_t)NN * KP1 * 2);        // 52.4 MB
  short* w1tH = (short*)alloc((size_t)NL * NP1 * KP1 * 2);  // 2.05 MB
  short* w1tL = (short*)alloc((size_t)NL * NP1 * KP1 * 2);
  short* w2tH = (short*)alloc((size_t)NL * NP2 * KP2 * 2);  // 1.95 MB
  short* w2tL = (short*)alloc((size_t)NL * NP2 * KP2 * 2);
  short* featH = (short*)alloc((size_t)2 * NB * FKP * 2);
  short* featL = (short*)alloc((size_t)2 * NB * FKP * 2);
  int* cnt    = (int*)alloc((size_t)NN * 4);
  int* rs     = (int*)alloc((size_t)(NN + 1) * 4);
  int* srcs   = (int*)alloc((size_t)NE * 4);
  int* attrs  = (int*)alloc((size_t)NE * 4);
  float* stats = (float*)alloc(600 * 4);
  float* scsh  = (float*)alloc(600 * 4);
  int* gstart  = (int*)alloc((size_t)(NB + 1) * 4);
  float* pg   = (float*)alloc((size_t)NB * D * 4);
  float* pt   = (float*)alloc((size_t)NB * D * 4);
  // total ~ 227 MB (no slab — GEMM1->GEMM2 intermediate lives in LDS)

  k_prepw<<<(NL * NP1 * KP1 + 255) / 256, 256, 0, stream>>>(W1, w1tH, w1tL, 300, 600, KP1, NP1);
  k_prepw<<<(NL * NP2 * KP2 + 255) / 256, 256, 0, stream>>>(W2, w2tH, w2tL, 600, 300, KP2, NP2);

  for (int v = 0; v < 2; ++v) {
    k_init_h<<<NN, 128, 0, stream>>>(xs[v], ae1, ae2, h);
    hipMemsetAsync(cnt, 0, (size_t)NN * 4, stream);
    k_count<<<(NE + 255) / 256, 256, 0, stream>>>(eis[v], cnt);
    k_scan<<<1, 1024, 0, stream>>>(cnt, rs);
    hipMemsetAsync(cnt, 0, (size_t)NN * 4, stream);
    k_bucket<<<(NE + 255) / 256, 256, 0, stream>>>(eis[v], eas[v], rs, cnt, srcs, attrs);

    for (int l = 0; l < NL; ++l) {
      if (l == 0)
        k_gather<false><<<NN, 128, 0, stream>>>(h, rs, srcs, attrs, ee1 + (size_t)l * 6 * D,
                                                ee2 + (size_t)l * 3 * D, nullptr, aggH, aggL);
      else
        k_gather<true><<<NN, 128, 0, stream>>>(h, rs, srcs, attrs, ee1 + (size_t)l * 6 * D,
                                               ee2 + (size_t)l * 3 * D, scsh, aggH, aggL);
      hipMemsetAsync(stats, 0, 600 * 4, stream);
      k_mlp<<<NN / 16, 256, 0, stream>>>(
          aggH, aggL,
          w1tH + (size_t)l * NP1 * KP1, w1tL + (size_t)l * NP1 * KP1,
          w2tH + (size_t)l * NP2 * KP2, w2tL + (size_t)l * NP2 * KP2,
          b1 + (size_t)l * 600, b2 + (size_t)l * 300, h, stats);
      k_bnfinal<<<1, 320, 0, stream>>>(stats, bng + (size_t)l * D, bnb + (size_t)l * D, scsh);
    }

    k_gstart<<<(NN + 255) / 256, 256, 0, stream>>>(bts[v], gstart);
    k_poolseg<<<NB, 128, 0, stream>>>(h, gstart, scsh, pg);
    k_gemm<true><<<dim3(NB / 128, (D + 127) / 128), 256, 0, stream>>>(pg, pW1, pb1, pt, NB, D, D);
    k_gemm<false><<<dim3(NB / 128, (D + 127) / 128), 256, 0, stream>>>(pt, pW2, pb2, pg, NB, D, D);
    k_norm<<<NB, 64, 0, stream>>>(pg, featH, featL, v * NB);
  }

  k_logits_mfma<<<dim3(4096 / 128, 4096 / 128), 256, 0, stream>>>(featH, featL, (float*)d_out);
  hipMemsetAsync((float*)d_out + (size_t)4096 * 4095, 0, (size_t)4096 * 4, stream);
}

// Round 8
// 4795.597 us; speedup vs baseline: 2.2604x; 1.8429x over previous
//
#include <hip/hip_runtime.h>

#define NN 81920
#define NE 180224
#define NB 2048
#define D 300
#define NL 5
#define KP1 320          // padded K for GEMM1 (agg planes stride)
#define NP1 640          // padded N for GEMM1
#define KP2 608          // padded K for GEMM2 (19 x 32)
#define NP2 320          // padded N for GEMM2
#define FKP 320          // feature planes stride (logits K)
#define LSTR 616         // LDS intermediate row stride (elems)
#define NBUCK 64         // BN-stats atomic buckets
#define P1FR (40 * 10 * 64 * 8)   // frag-major W1T elems per layer = 204800
#define P2FR (20 * 19 * 64 * 8)   // frag-major W2T elems per layer = 194560

static constexpr float TEMP_INV = 25.0f;   // 1/0.04
static constexpr float BN_EPS_C = 1e-5f;

typedef __attribute__((ext_vector_type(8))) short short8;
typedef __attribute__((ext_vector_type(4))) float f32x4;

__device__ inline void split_bf16(float v, short& hi, short& lo) {
  unsigned u = __float_as_uint(v);
  hi = (short)(u >> 16);
  float r = v - __uint_as_float(u & 0xffff0000u);
  lo = (short)(__float_as_uint(r) >> 16);
}

// ---------------- init h = atom_emb1[x0] + atom_emb2[x1] ----------------
__global__ void k_init_h(const int* __restrict__ x, const float* __restrict__ ae1,
                         const float* __restrict__ ae2, float* __restrict__ h) {
  int i = blockIdx.x;
  int i0 = x[2 * i], i1 = x[2 * i + 1];
  const float* r1 = ae1 + (size_t)i0 * D;
  const float* r2 = ae2 + (size_t)i1 * D;
  float* ho = h + (size_t)i * D;
  for (int f = threadIdx.x; f < D; f += blockDim.x) ho[f] = r1[f] + r2[f];
}

// ---------------- CSR build ----------------
__global__ void k_count(const int* __restrict__ ei, int* __restrict__ cnt) {
  int e = blockIdx.x * blockDim.x + threadIdx.x;
  if (e < NE) atomicAdd(&cnt[ei[NE + e]], 1);
}

__global__ void k_scan(const int* __restrict__ cnt, int* __restrict__ rs) {
  __shared__ int sdata[1024];
  int t = threadIdx.x;
  int base = t * 80;                 // 1024*80 == 81920
  int s = 0;
  for (int j = 0; j < 80; ++j) s += cnt[base + j];
  sdata[t] = s;
  __syncthreads();
  for (int off = 1; off < 1024; off <<= 1) {
    int v = (t >= off) ? sdata[t - off] : 0;
    __syncthreads();
    sdata[t] += v;
    __syncthreads();
  }
  int run = sdata[t] - s;
  for (int j = 0; j < 80; ++j) { rs[base + j] = run; run += cnt[base + j]; }
  if (t == 1023) rs[NN] = run;
}

__global__ void k_bucket(const int* __restrict__ ei, const int* __restrict__ ea,
                         const int* __restrict__ rs, int* __restrict__ fill,
                         int* __restrict__ srcs, int* __restrict__ attrs) {
  int e = blockIdx.x * blockDim.x + threadIdx.x;
  if (e >= NE) return;
  int d = ei[NE + e];
  int p = rs[d] + atomicAdd(&fill[d], 1);
  srcs[p] = ei[e];
  attrs[p] = ea[2 * e] | (ea[2 * e + 1] << 8);
}

// ---------------- gather (+ fused BN-apply+ReLU of previous layer) ----------------
template <bool BN>
__global__ void k_gather(const float* __restrict__ h, const int* __restrict__ rs,
                         const int* __restrict__ srcs, const int* __restrict__ attrs,
                         const float* __restrict__ T1, const float* __restrict__ T2,
                         const float* __restrict__ scsh,
                         short* __restrict__ aggH, short* __restrict__ aggL) {
  int i = blockIdx.x;
  int j0 = rs[i], j1 = rs[i + 1];
  int t = threadIdx.x;               // 128
  int f0 = t, f1 = t + 128, f2 = t + 256;
  float sc0 = 0, sh0 = 0, sc1 = 0, sh1 = 0, sc2 = 0, sh2 = 0;
  if (BN) {
    sc0 = scsh[f0]; sh0 = scsh[D + f0];
    sc1 = scsh[f1]; sh1 = scsh[D + f1];
    if (f2 < D) { sc2 = scsh[f2]; sh2 = scsh[D + f2]; }
  }
  auto u0 = [&](float x) { return BN ? fmaxf(fmaf(x, sc0, sh0), 0.f) : x; };
  auto u1 = [&](float x) { return BN ? fmaxf(fmaf(x, sc1, sh1), 0.f) : x; };
  auto u2 = [&](float x) { return BN ? fmaxf(fmaf(x, sc2, sh2), 0.f) : x; };
  const float* hi = h + (size_t)i * D;
  float a0 = u0(hi[f0]) + T1[4 * D + f0] + T2[f0];
  float a1 = u1(hi[f1]) + T1[4 * D + f1] + T2[f1];
  float a2 = (f2 < D) ? (u2(hi[f2]) + T1[4 * D + f2] + T2[f2]) : 0.f;
  for (int j = j0; j < j1; ++j) {
    int s = srcs[j];
    int at = attrs[j];
    const float* hs = h + (size_t)s * D;
    const float* t1 = T1 + (size_t)(at & 255) * D;
    const float* t2 = T2 + (size_t)(at >> 8) * D;
    a0 += u0(hs[f0]) + t1[f0] + t2[f0];
    a1 += u1(hs[f1]) + t1[f1] + t2[f1];
    if (f2 < D) a2 += u2(hs[f2]) + t1[f2] + t2[f2];
  }
  size_t base = (size_t)i * KP1;
  short hh, ll;
  split_bf16(a0, hh, ll); aggH[base + f0] = hh; aggL[base + f0] = ll;
  split_bf16(a1, hh, ll); aggH[base + f1] = hh; aggL[base + f1] = ll;
  if (f2 < KP1) {
    split_bf16(a2, hh, ll); aggH[base + f2] = hh; aggL[base + f2] = ll;
  }
}

// ---------------- W1T -> fragment-major split planes ----------------
// flat = ((n*10 + t)*64 + lane)*8 + e ; row = n*16+(lane&15), k = t*32+(lane>>4)*8+e
__global__ void k_prepw1(const float* __restrict__ W, short* __restrict__ TH,
                         short* __restrict__ TL) {
  int idx = blockIdx.x * blockDim.x + threadIdx.x;
  if (idx >= NL * P1FR) return;
  int l5 = idx / P1FR, r = idx % P1FR;
  int e = r & 7, l = (r >> 3) & 63, t = (r >> 9) % 10, n = (r >> 9) / 10;
  int row = n * 16 + (l & 15);          // output col of W1 (<640)
  int k = t * 32 + (l >> 4) * 8 + e;    // input dim (<320)
  float v = (row < 600 && k < 300) ? W[(size_t)l5 * 300 * 600 + (size_t)k * 600 + row] : 0.f;
  short hi, lo;
  split_bf16(v, hi, lo);
  TH[idx] = hi;
  TL[idx] = lo;
}

// ---------------- W2T -> fragment-major split planes ----------------
__global__ void k_prepw2(const float* __restrict__ W, short* __restrict__ TH,
                         short* __restrict__ TL) {
  int idx = blockIdx.x * blockDim.x + threadIdx.x;
  if (idx >= NL * P2FR) return;
  int l5 = idx / P2FR, r = idx % P2FR;
  int e = r & 7, l = (r >> 3) & 63, t = (r >> 9) % 19, n = (r >> 9) / 19;
  int row = n * 16 + (l & 15);          // output col of W2 (<320)
  int k = t * 32 + (l >> 4) * 8 + e;    // intermediate dim (<608)
  float v = (row < 300 && k < 600) ? W[(size_t)l5 * 600 * 300 + (size_t)k * 300 + row] : 0.f;
  short hi, lo;
  split_bf16(v, hi, lo);
  TH[idx] = hi;
  TL[idx] = lo;
}

// ---------------- fused GIN MLP, 32 rows/block, frag-major weights, bucketed stats ----
__global__ __launch_bounds__(256, 2) void k_mlp(
    const short* __restrict__ AH, const short* __restrict__ AL,
    const short* __restrict__ B1H, const short* __restrict__ B1L,
    const short* __restrict__ B2H, const short* __restrict__ B2L,
    const float* __restrict__ bias1, const float* __restrict__ bias2,
    float* __restrict__ hout, float* __restrict__ stats) {
  __shared__ __align__(16) short iH[32][LSTR];
  __shared__ __align__(16) short iL[32][LSTR];
  int lane = threadIdx.x & 63;
  int w = threadIdx.x >> 6;
  int r0 = blockIdx.x * 32;
  int rl = lane & 15;
  int g = lane >> 4;
  int kg = g * 8;
  // ---- GEMM1: wave w -> cols [w*160, w*160+160), rows r0..r0+31 ----
  {
    f32x4 acc[2][10] = {};
    for (int t = 0; t < 10; ++t) {
      int kk = t * 32 + kg;
      short8 a0H = *(const short8*)(AH + (size_t)(r0 + rl) * KP1 + kk);
      short8 a0L = *(const short8*)(AL + (size_t)(r0 + rl) * KP1 + kk);
      short8 a1H = *(const short8*)(AH + (size_t)(r0 + 16 + rl) * KP1 + kk);
      short8 a1L = *(const short8*)(AL + (size_t)(r0 + 16 + rl) * KP1 + kk);
#pragma unroll
      for (int cf = 0; cf < 10; ++cf) {
        int n = w * 10 + cf;
        size_t off = ((size_t)(n * 10 + t) * 64 + lane) * 8;
        short8 bH = *(const short8*)(B1H + off);
        short8 bL = *(const short8*)(B1L + off);
        acc[0][cf] = __builtin_amdgcn_mfma_f32_16x16x32_bf16(a0H, bH, acc[0][cf], 0, 0, 0);
        acc[0][cf] = __builtin_amdgcn_mfma_f32_16x16x32_bf16(a0H, bL, acc[0][cf], 0, 0, 0);
        acc[0][cf] = __builtin_amdgcn_mfma_f32_16x16x32_bf16(a0L, bH, acc[0][cf], 0, 0, 0);
        acc[1][cf] = __builtin_amdgcn_mfma_f32_16x16x32_bf16(a1H, bH, acc[1][cf], 0, 0, 0);
        acc[1][cf] = __builtin_amdgcn_mfma_f32_16x16x32_bf16(a1H, bL, acc[1][cf], 0, 0, 0);
        acc[1][cf] = __builtin_amdgcn_mfma_f32_16x16x32_bf16(a1L, bH, acc[1][cf], 0, 0, 0);
      }
    }
#pragma unroll
    for (int cf = 0; cf < 10; ++cf) {
      int col = w * 160 + cf * 16 + rl;
      float bv = (col < 600) ? bias1[col] : 0.f;
#pragma unroll
      for (int rt = 0; rt < 2; ++rt) {
#pragma unroll
        for (int i = 0; i < 4; ++i) {
          int row = rt * 16 + g * 4 + i;
          float v = fmaxf(acc[rt][cf][i] + bv, 0.f);
          short hi, lo;
          split_bf16(v, hi, lo);
          if (col < KP2) { iH[row][col] = hi; iL[row][col] = lo; }
        }
      }
    }
  }
  __syncthreads();
  // ---- GEMM2: wave w -> cols [w*80, w*80+80), rows r0..r0+31 ----
  f32x4 a2[2][5] = {};
  for (int t = 0; t < 19; ++t) {
    int kk = t * 32 + kg;
    short8 x0H = *(const short8*)&iH[rl][kk];
    short8 x0L = *(const short8*)&iL[rl][kk];
    short8 x1H = *(const short8*)&iH[16 + rl][kk];
    short8 x1L = *(const short8*)&iL[16 + rl][kk];
#pragma unroll
    for (int cf = 0; cf < 5; ++cf) {
      int n = w * 5 + cf;
      size_t off = ((size_t)(n * 19 + t) * 64 + lane) * 8;
      short8 bH = *(const short8*)(B2H + off);
      short8 bL = *(const short8*)(B2L + off);
      a2[0][cf] = __builtin_amdgcn_mfma_f32_16x16x32_bf16(x0H, bH, a2[0][cf], 0, 0, 0);
      a2[0][cf] = __builtin_amdgcn_mfma_f32_16x16x32_bf16(x0H, bL, a2[0][cf], 0, 0, 0);
      a2[0][cf] = __builtin_amdgcn_mfma_f32_16x16x32_bf16(x0L, bH, a2[0][cf], 0, 0, 0);
      a2[1][cf] = __builtin_amdgcn_mfma_f32_16x16x32_bf16(x1H, bH, a2[1][cf], 0, 0, 0);
      a2[1][cf] = __builtin_amdgcn_mfma_f32_16x16x32_bf16(x1H, bL, a2[1][cf], 0, 0, 0);
      a2[1][cf] = __builtin_amdgcn_mfma_f32_16x16x32_bf16(x1L, bH, a2[1][cf], 0, 0, 0);
    }
  }
  int bk = (blockIdx.x & (NBUCK - 1)) * 600;
#pragma unroll
  for (int cf = 0; cf < 5; ++cf) {
    int col = w * 80 + cf * 16 + rl;
    float bv = (col < D) ? bias2[col] : 0.f;
    float s = 0.f, q = 0.f;
#pragma unroll
    for (int rt = 0; rt < 2; ++rt) {
#pragma unroll
      for (int i = 0; i < 4; ++i) {
        int row = r0 + rt * 16 + g * 4 + i;
        float v = a2[rt][cf][i] + bv;
        if (col < D) hout[(size_t)row * D + col] = v;
        s += v; q += v * v;
      }
    }
    s += __shfl_xor(s, 16); s += __shfl_xor(s, 32);
    q += __shfl_xor(q, 16); q += __shfl_xor(q, 32);
    if (g == 0 && col < D) {
      atomicAdd(&stats[bk + col], s);
      atomicAdd(&stats[bk + 300 + col], q);
    }
  }
}

// ---------------- fp32 tiled GEMM (projector only) ----------------
template <bool RELU>
__global__ __launch_bounds__(256) void k_gemm(const float* __restrict__ A,
                                              const float* __restrict__ Bm,
                                              const float* __restrict__ bias,
                                              float* __restrict__ C,
                                              int M, int K, int Nc) {
  __shared__ float As[8][132];
  __shared__ float Bs[8][132];
  int tid = threadIdx.x;
  int tx = tid & 15, ty = tid >> 4;
  int m0 = blockIdx.x * 128, n0 = blockIdx.y * 128;
  float acc[8][8] = {};
  int ar = tid >> 1, akq = (tid & 1) * 4;
  int bk = tid >> 5, bn = (tid & 31) * 4;
  for (int kk = 0; kk < K; kk += 8) {
    {
      int gr = m0 + ar, gk = kk + akq;
      if (gr < M && gk + 3 < K) {
        float4 v = *(const float4*)(A + (size_t)gr * K + gk);
        As[akq + 0][ar] = v.x; As[akq + 1][ar] = v.y;
        As[akq + 2][ar] = v.z; As[akq + 3][ar] = v.w;
      } else {
#pragma unroll
        for (int u = 0; u < 4; ++u)
          As[akq + u][ar] = (gr < M && gk + u < K) ? A[(size_t)gr * K + gk + u] : 0.f;
      }
    }
    {
      int gk = kk + bk, gn = n0 + bn;
      if (gk < K && gn + 3 < Nc) {
        *(float4*)&Bs[bk][bn] = *(const float4*)(Bm + (size_t)gk * Nc + gn);
      } else {
#pragma unroll
        for (int u = 0; u < 4; ++u)
          Bs[bk][bn + u] = (gk < K && gn + u < Nc) ? Bm[(size_t)gk * Nc + gn + u] : 0.f;
      }
    }
    __syncthreads();
#pragma unroll
    for (int k = 0; k < 8; ++k) {
      float4 a0 = *(const float4*)&As[k][ty * 8];
      float4 a1 = *(const float4*)&As[k][ty * 8 + 4];
      float4 b0 = *(const float4*)&Bs[k][tx * 8];
      float4 b1 = *(const float4*)&Bs[k][tx * 8 + 4];
      float av[8] = {a0.x, a0.y, a0.z, a0.w, a1.x, a1.y, a1.z, a1.w};
      float bv[8] = {b0.x, b0.y, b0.z, b0.w, b1.x, b1.y, b1.z, b1.w};
#pragma unroll
      for (int i = 0; i < 8; ++i)
#pragma unroll
        for (int j = 0; j < 8; ++j) acc[i][j] = fmaf(av[i], bv[j], acc[i][j]);
    }
    __syncthreads();
  }
  int rbase = m0 + ty * 8, cbase = n0 + tx * 8;
#pragma unroll
  for (int i = 0; i < 8; ++i) {
    int r = rbase + i;
    if (r >= M) break;
#pragma unroll
    for (int j = 0; j < 8; ++j) {
      int c = cbase + j;
      if (c >= Nc) continue;
      float v = acc[i][j] + bias[c];
      if (RELU) v = fmaxf(v, 0.f);
      C[(size_t)r * Nc + c] = v;
    }
  }
}

// ---------------- BN finalize (bucketed stats -> scale/shift) ----------------
__global__ void k_bnfinal(const float* __restrict__ stats, const float* __restrict__ g,
                          const float* __restrict__ b, float* __restrict__ scsh) {
  int t = threadIdx.x;
  if (t >= D) return;
  float s = 0.f, q = 0.f;
  for (int bk = 0; bk < NBUCK; ++bk) {
    s += stats[bk * 600 + t];
    q += stats[bk * 600 + 300 + t];
  }
  float mean = s * (1.0f / NN);
  float var = q * (1.0f / NN) - mean * mean;
  float inv = rsqrtf(var + BN_EPS_C);
  float sc = g[t] * inv;
  scsh[t] = sc;
  scsh[D + t] = b[t] - mean * sc;
}

// ---------------- pooling (batch sorted) + fused last-layer BN ----------------
__global__ void k_gstart(const int* __restrict__ batch, int* __restrict__ gs) {
  int i = blockIdx.x * blockDim.x + threadIdx.x;
  if (i >= NN) return;
  int b = batch[i];
  int bp = (i == 0) ? -1 : batch[i - 1];
  for (int q = bp + 1; q <= b; ++q) gs[q] = i;
  if (i == NN - 1)
    for (int q = b + 1; q <= NB; ++q) gs[q] = NN;
}

__global__ void k_poolseg(const float* __restrict__ h, const int* __restrict__ gs,
                          const float* __restrict__ scsh, float* __restrict__ g) {
  int b = blockIdx.x;
  int j0 = gs[b], j1 = gs[b + 1];
  int t = threadIdx.x;               // 128
  float s0 = 0, s1 = 0, s2 = 0;
  int c2 = t + 256;
  for (int j = j0; j < j1; ++j) {
    const float* row = h + (size_t)j * D;
    s0 += row[t];
    s1 += row[t + 128];
    if (c2 < D) s2 += row[c2];
  }
  bool nz = j1 > j0;
  float invc = nz ? 1.f / (float)(j1 - j0) : 0.f;
  float* go = g + (size_t)b * D;
  go[t] = nz ? fmaf(s0 * invc, scsh[t], scsh[D + t]) : 0.f;
  go[t + 128] = nz ? fmaf(s1 * invc, scsh[t + 128], scsh[D + t + 128]) : 0.f;
  if (c2 < D) go[c2] = nz ? fmaf(s2 * invc, scsh[c2], scsh[D + c2]) : 0.f;
}

// ---------------- L2 normalize -> split feature planes [4096, FKP] ----------------
__global__ void k_norm(const float* __restrict__ pin, short* __restrict__ FH,
                       short* __restrict__ FL, int ro) {
  int b = blockIdx.x;
  int t = threadIdx.x;               // 64
  const float* row = pin + (size_t)b * D;
  float q = 0;
  for (int c = t; c < D; c += 64) { float v = row[c]; q += v * v; }
#pragma unroll
  for (int off = 32; off > 0; off >>= 1) q += __shfl_down(q, off);
  q = __shfl(q, 0);
  float inv = 1.f / fmaxf(sqrtf(q), 1e-12f);
  size_t base = (size_t)(ro + b) * FKP;
  for (int c = t; c < FKP; c += 64) {
    float v = (c < D) ? row[c] * inv : 0.f;
    short hi, lo;
    split_bf16(v, hi, lo);
    FH[base + c] = hi;
    FL[base + c] = lo;
  }
}

// ---------------- MFMA sim = F F^T fused with NT-Xent logits layout ----------------
__global__ __launch_bounds__(256) void k_logits_mfma(const short* __restrict__ FH,
                                                     const short* __restrict__ FL,
                                                     float* __restrict__ out) {
  int lane = threadIdx.x & 63;
  int w = threadIdx.x >> 6;
  int m0 = blockIdx.x * 128 + (w >> 1) * 64;
  int n0 = blockIdx.y * 128 + (w & 1) * 64;
  int rl = lane & 15;
  int kg = (lane >> 4) * 8;
  f32x4 acc[4][4] = {};
  for (int k0 = 0; k0 < FKP; k0 += 32) {
    int kk = k0 + kg;
    short8 aH[4], aL[4], bH[4], bL[4];
#pragma unroll
    for (int rf = 0; rf < 4; ++rf) {
      size_t off = (size_t)(m0 + rf * 16 + rl) * FKP + kk;
      aH[rf] = *(const short8*)(FH + off);
      aL[rf] = *(const short8*)(FL + off);
    }
#pragma unroll
    for (int cf = 0; cf < 4; ++cf) {
      size_t off = (size_t)(n0 + cf * 16 + rl) * FKP + kk;
      bH[cf] = *(const short8*)(FH + off);
      bL[cf] = *(const short8*)(FL + off);
    }
#pragma unroll
    for (int rf = 0; rf < 4; ++rf)
#pragma unroll
      for (int cf = 0; cf < 4; ++cf) {
        acc[rf][cf] = __builtin_amdgcn_mfma_f32_16x16x32_bf16(aH[rf], bH[cf], acc[rf][cf], 0, 0, 0);
        acc[rf][cf] = __builtin_amdgcn_mfma_f32_16x16x32_bf16(aH[rf], bL[cf], acc[rf][cf], 0, 0, 0);
        acc[rf][cf] = __builtin_amdgcn_mfma_f32_16x16x32_bf16(aL[rf], bH[cf], acc[rf][cf], 0, 0, 0);
      }
  }
#pragma unroll
  for (int rf = 0; rf < 4; ++rf) {
#pragma unroll
    for (int cf = 0; cf < 4; ++cf) {
      int c = n0 + cf * 16 + rl;
#pragma unroll
      for (int i = 0; i < 4; ++i) {
        int r = m0 + rf * 16 + (lane >> 4) * 4 + i;
        if (c == r) continue;
        float v = acc[rf][cf][i] * TEMP_INV;
        int posj = (r + NB) & 4095;
        int slot = (c == posj) ? 0 : (1 + c - (c > r) - (c > posj));
        out[(size_t)r * 4095 + slot] = v;
      }
    }
  }
}

// ---------------- host ----------------
extern "C" void kernel_launch(void* const* d_in, const int* in_sizes, int n_in,
                              void* d_out, int out_size, void* d_ws, size_t ws_size,
                              hipStream_t stream) {
  const int* xs[2] = {(const int*)d_in[0], (const int*)d_in[4]};
  const int* eis[2] = {(const int*)d_in[1], (const int*)d_in[5]};
  const int* eas[2] = {(const int*)d_in[2], (const int*)d_in[6]};
  const int* bts[2] = {(const int*)d_in[3], (const int*)d_in[7]};
  const float* ae1 = (const float*)d_in[8];
  const float* ae2 = (const float*)d_in[9];
  const float* ee1 = (const float*)d_in[10];
  const float* ee2 = (const float*)d_in[11];
  const float* W1 = (const float*)d_in[12];
  const float* b1 = (const float*)d_in[13];
  const float* W2 = (const float*)d_in[14];
  const float* b2 = (const float*)d_in[15];
  const float* bng = (const float*)d_in[16];
  const float* bnb = (const float*)d_in[17];
  const float* pW1 = (const float*)d_in[18];
  const float* pb1 = (const float*)d_in[19];
  const float* pW2 = (const float*)d_in[20];
  const float* pb2 = (const float*)d_in[21];

  char* p = (char*)d_ws;
  auto alloc = [&](size_t bytes) -> void* {
    void* q = (void*)p;
    p += (bytes + 255) & ~(size_t)255;
    return q;
  };
  float* h    = (float*)alloc((size_t)NN * D * 4);          // 98.3 MB
  short* aggH = (short*)alloc((size_t)NN * KP1 * 2);        // 52.4 MB
  short* aggL = (short*)alloc((size_t)NN * KP1 * 2);        // 52.4 MB
  short* w1tH = (short*)alloc((size_t)NL * P1FR * 2);       // 2.05 MB
  short* w1tL = (short*)alloc((size_t)NL * P1FR * 2);
  short* w2tH = (short*)alloc((size_t)NL * P2FR * 2);       // 1.95 MB
  short* w2tL = (short*)alloc((size_t)NL * P2FR * 2);
  short* featH = (short*)alloc((size_t)2 * NB * FKP * 2);
  short* featL = (short*)alloc((size_t)2 * NB * FKP * 2);
  int* cnt    = (int*)alloc((size_t)NN * 4);
  int* rs     = (int*)alloc((size_t)(NN + 1) * 4);
  int* srcs   = (int*)alloc((size_t)NE * 4);
  int* attrs  = (int*)alloc((size_t)NE * 4);
  float* stats = (float*)alloc((size_t)NBUCK * 600 * 4);    // 153.6 KB
  float* scsh  = (float*)alloc(600 * 4);
  int* gstart  = (int*)alloc((size_t)(NB + 1) * 4);
  float* pg   = (float*)alloc((size_t)NB * D * 4);
  float* pt   = (float*)alloc((size_t)NB * D * 4);
  // total ~ 227 MB

  k_prepw1<<<(NL * P1FR + 255) / 256, 256, 0, stream>>>(W1, w1tH, w1tL);
  k_prepw2<<<(NL * P2FR + 255) / 256, 256, 0, stream>>>(W2, w2tH, w2tL);

  for (int v = 0; v < 2; ++v) {
    k_init_h<<<NN, 128, 0, stream>>>(xs[v], ae1, ae2, h);
    hipMemsetAsync(cnt, 0, (size_t)NN * 4, stream);
    k_count<<<(NE + 255) / 256, 256, 0, stream>>>(eis[v], cnt);
    k_scan<<<1, 1024, 0, stream>>>(cnt, rs);
    hipMemsetAsync(cnt, 0, (size_t)NN * 4, stream);
    k_bucket<<<(NE + 255) / 256, 256, 0, stream>>>(eis[v], eas[v], rs, cnt, srcs, attrs);

    for (int l = 0; l < NL; ++l) {
      if (l == 0)
        k_gather<false><<<NN, 128, 0, stream>>>(h, rs, srcs, attrs, ee1 + (size_t)l * 6 * D,
                                                ee2 + (size_t)l * 3 * D, nullptr, aggH, aggL);
      else
        k_gather<true><<<NN, 128, 0, stream>>>(h, rs, srcs, attrs, ee1 + (size_t)l * 6 * D,
                                               ee2 + (size_t)l * 3 * D, scsh, aggH, aggL);
      hipMemsetAsync(stats, 0, (size_t)NBUCK * 600 * 4, stream);
      k_mlp<<<NN / 32, 256, 0, stream>>>(
          aggH, aggL,
          w1tH + (size_t)l * P1FR, w1tL + (size_t)l * P1FR,
          w2tH + (size_t)l * P2FR, w2tL + (size_t)l * P2FR,
          b1 + (size_t)l * 600, b2 + (size_t)l * 300, h, stats);
      k_bnfinal<<<1, 320, 0, stream>>>(stats, bng + (size_t)l * D, bnb + (size_t)l * D, scsh);
    }

    k_gstart<<<(NN + 255) / 256, 256, 0, stream>>>(bts[v], gstart);
    k_poolseg<<<NB, 128, 0, stream>>>(h, gstart, scsh, pg);
    k_gemm<true><<<dim3(NB / 128, (D + 127) / 128), 256, 0, stream>>>(pg, pW1, pb1, pt, NB, D, D);
    k_gemm<false><<<dim3(NB / 128, (D + 127) / 128), 256, 0, stream>>>(pt, pW2, pb2, pg, NB, D, D);
    k_norm<<<NB, 64, 0, stream>>>(pg, featH, featL, v * NB);
  }

  k_logits_mfma<<<dim3(4096 / 128, 4096 / 128), 256, 0, stream>>>(featH, featL, (float*)d_out);
  hipMemsetAsync((float*)d_out + (size_t)4096 * 4095, 0, (size_t)4096 * 4, stream);
}

// Round 9
// 4733.641 us; speedup vs baseline: 2.2900x; 1.0131x over previous
//
#include <hip/hip_runtime.h>

#define NN 81920
#define NE 180224
#define NB 2048
#define D 300
#define NL 5
#define KP1 320          // padded K for GEMM1 (agg planes stride)
#define KP2 608          // padded K for GEMM2 (19 x 32)
#define FKP 320          // feature planes stride (logits K)
#define LSTR 616         // LDS intermediate row stride (elems)
#define NBUCK 64         // BN-stats atomic buckets
#define P1FR (40 * 10 * 64 * 8)   // frag-major W1T elems per layer = 204800
#define P2FR (20 * 19 * 64 * 8)   // frag-major W2T elems per layer = 194560

static constexpr float TEMP_INV = 25.0f;   // 1/0.04
static constexpr float BN_EPS_C = 1e-5f;

typedef __attribute__((ext_vector_type(8))) short short8;
typedef __attribute__((ext_vector_type(4))) float f32x4;

#define MFMA __builtin_amdgcn_mfma_f32_16x16x32_bf16

__device__ inline void split_bf16(float v, short& hi, short& lo) {
  unsigned u = __float_as_uint(v);
  hi = (short)(u >> 16);
  float r = v - __uint_as_float(u & 0xffff0000u);
  lo = (short)(__float_as_uint(r) >> 16);
}

// ---------------- init h = atom_emb1[x0] + atom_emb2[x1] ----------------
__global__ void k_init_h(const int* __restrict__ x, const float* __restrict__ ae1,
                         const float* __restrict__ ae2, float* __restrict__ h) {
  int i = blockIdx.x;
  int i0 = x[2 * i], i1 = x[2 * i + 1];
  const float* r1 = ae1 + (size_t)i0 * D;
  const float* r2 = ae2 + (size_t)i1 * D;
  float* ho = h + (size_t)i * D;
  for (int f = threadIdx.x; f < D; f += blockDim.x) ho[f] = r1[f] + r2[f];
}

// ---------------- CSR build ----------------
__global__ void k_count(const int* __restrict__ ei, int* __restrict__ cnt) {
  int e = blockIdx.x * blockDim.x + threadIdx.x;
  if (e < NE) atomicAdd(&cnt[ei[NE + e]], 1);
}

__global__ void k_scan(const int* __restrict__ cnt, int* __restrict__ rs) {
  __shared__ int sdata[1024];
  int t = threadIdx.x;
  int base = t * 80;                 // 1024*80 == 81920
  int s = 0;
  for (int j = 0; j < 80; ++j) s += cnt[base + j];
  sdata[t] = s;
  __syncthreads();
  for (int off = 1; off < 1024; off <<= 1) {
    int v = (t >= off) ? sdata[t - off] : 0;
    __syncthreads();
    sdata[t] += v;
    __syncthreads();
  }
  int run = sdata[t] - s;
  for (int j = 0; j < 80; ++j) { rs[base + j] = run; run += cnt[base + j]; }
  if (t == 1023) rs[NN] = run;
}

__global__ void k_bucket(const int* __restrict__ ei, const int* __restrict__ ea,
                         const int* __restrict__ rs, int* __restrict__ fill,
                         int* __restrict__ srcs, int* __restrict__ attrs) {
  int e = blockIdx.x * blockDim.x + threadIdx.x;
  if (e >= NE) return;
  int d = ei[NE + e];
  int p = rs[d] + atomicAdd(&fill[d], 1);
  srcs[p] = ei[e];
  attrs[p] = ea[2 * e] | (ea[2 * e + 1] << 8);
}

// ---------------- gather (+ fused BN-apply+ReLU of previous layer) ----------------
template <bool BN>
__global__ void k_gather(const float* __restrict__ h, const int* __restrict__ rs,
                         const int* __restrict__ srcs, const int* __restrict__ attrs,
                         const float* __restrict__ T1, const float* __restrict__ T2,
                         const float* __restrict__ scsh,
                         short* __restrict__ aggH, short* __restrict__ aggL) {
  int i = blockIdx.x;
  int j0 = rs[i], j1 = rs[i + 1];
  int t = threadIdx.x;               // 128
  int f0 = t, f1 = t + 128, f2 = t + 256;
  float sc0 = 0, sh0 = 0, sc1 = 0, sh1 = 0, sc2 = 0, sh2 = 0;
  if (BN) {
    sc0 = scsh[f0]; sh0 = scsh[D + f0];
    sc1 = scsh[f1]; sh1 = scsh[D + f1];
    if (f2 < D) { sc2 = scsh[f2]; sh2 = scsh[D + f2]; }
  }
  auto u0 = [&](float x) { return BN ? fmaxf(fmaf(x, sc0, sh0), 0.f) : x; };
  auto u1 = [&](float x) { return BN ? fmaxf(fmaf(x, sc1, sh1), 0.f) : x; };
  auto u2 = [&](float x) { return BN ? fmaxf(fmaf(x, sc2, sh2), 0.f) : x; };
  const float* hi = h + (size_t)i * D;
  float a0 = u0(hi[f0]) + T1[4 * D + f0] + T2[f0];
  float a1 = u1(hi[f1]) + T1[4 * D + f1] + T2[f1];
  float a2 = (f2 < D) ? (u2(hi[f2]) + T1[4 * D + f2] + T2[f2]) : 0.f;
  for (int j = j0; j < j1; ++j) {
    int s = srcs[j];
    int at = attrs[j];
    const float* hs = h + (size_t)s * D;
    const float* t1 = T1 + (size_t)(at & 255) * D;
    const float* t2 = T2 + (size_t)(at >> 8) * D;
    a0 += u0(hs[f0]) + t1[f0] + t2[f0];
    a1 += u1(hs[f1]) + t1[f1] + t2[f1];
    if (f2 < D) a2 += u2(hs[f2]) + t1[f2] + t2[f2];
  }
  size_t base = (size_t)i * KP1;
  short hh, ll;
  split_bf16(a0, hh, ll); aggH[base + f0] = hh; aggL[base + f0] = ll;
  split_bf16(a1, hh, ll); aggH[base + f1] = hh; aggL[base + f1] = ll;
  if (f2 < KP1) {
    split_bf16(a2, hh, ll); aggH[base + f2] = hh; aggL[base + f2] = ll;
  }
}

// ---------------- W1T -> fragment-major split planes ----------------
__global__ void k_prepw1(const float* __restrict__ W, short* __restrict__ TH,
                         short* __restrict__ TL) {
  int idx = blockIdx.x * blockDim.x + threadIdx.x;
  if (idx >= NL * P1FR) return;
  int l5 = idx / P1FR, r = idx % P1FR;
  int e = r & 7, l = (r >> 3) & 63, t = (r >> 9) % 10, n = (r >> 9) / 10;
  int row = n * 16 + (l & 15);          // output col of W1 (<640)
  int k = t * 32 + (l >> 4) * 8 + e;    // input dim (<320)
  float v = (row < 600 && k < 300) ? W[(size_t)l5 * 300 * 600 + (size_t)k * 600 + row] : 0.f;
  short hi, lo;
  split_bf16(v, hi, lo);
  TH[idx] = hi;
  TL[idx] = lo;
}

// ---------------- W2T -> fragment-major split planes ----------------
__global__ void k_prepw2(const float* __restrict__ W, short* __restrict__ TH,
                         short* __restrict__ TL) {
  int idx = blockIdx.x * blockDim.x + threadIdx.x;
  if (idx >= NL * P2FR) return;
  int l5 = idx / P2FR, r = idx % P2FR;
  int e = r & 7, l = (r >> 3) & 63, t = (r >> 9) % 19, n = (r >> 9) / 19;
  int row = n * 16 + (l & 15);          // output col of W2 (<320)
  int k = t * 32 + (l >> 4) * 8 + e;    // intermediate dim (<608)
  float v = (row < 300 && k < 600) ? W[(size_t)l5 * 600 * 300 + (size_t)k * 300 + row] : 0.f;
  short hi, lo;
  split_bf16(v, hi, lo);
  TH[idx] = hi;
  TL[idx] = lo;
}

// ---------------- fused GIN MLP, 32 rows/block, software-pipelined ----------------
__global__ __launch_bounds__(256, 2) void k_mlp(
    const short* __restrict__ AH, const short* __restrict__ AL,
    const short* __restrict__ B1H, const short* __restrict__ B1L,
    const short* __restrict__ B2H, const short* __restrict__ B2L,
    const float* __restrict__ bias1, const float* __restrict__ bias2,
    float* __restrict__ hout, float* __restrict__ stats) {
  __shared__ __align__(16) short iH[32][LSTR];
  __shared__ __align__(16) short iL[32][LSTR];
  int lane = threadIdx.x & 63;
  int w = threadIdx.x >> 6;
  int r0 = blockIdx.x * 32;
  int rl = lane & 15;
  int g = lane >> 4;
  int kg = g * 8;

  const short* pA0H = AH + (size_t)(r0 + rl) * KP1 + kg;
  const short* pA0L = AL + (size_t)(r0 + rl) * KP1 + kg;
  const short* pA1H = AH + (size_t)(r0 + 16 + rl) * KP1 + kg;
  const short* pA1L = AL + (size_t)(r0 + 16 + rl) * KP1 + kg;
  // W1 frag-major: elem offset = n*5120 + t*512 + lane*8  (n = w*10 + cf)
  const short* B1Hw = B1H + (size_t)w * 10 * 5120 + (size_t)lane * 8;
  const short* B1Lw = B1L + (size_t)w * 10 * 5120 + (size_t)lane * 8;
  // W2 frag-major: elem offset = n*9728 + t*512 + lane*8   (n = w*5 + cf)
  const short* B2Hw = B2H + (size_t)w * 5 * 9728 + (size_t)lane * 8;
  const short* B2Lw = B2L + (size_t)w * 5 * 9728 + (size_t)lane * 8;

  // ================= GEMM1: pipelined (B half-step ahead, A full-step ahead) ========
  {
    f32x4 acc[2][10] = {};
    short8 aC[4], aN[4];
    short8 bC[10], bN[10];          // 5 cf x {H,L}
    aC[0] = *(const short8*)pA0H;
    aC[1] = *(const short8*)pA0L;
    aC[2] = *(const short8*)pA1H;
    aC[3] = *(const short8*)pA1L;
#pragma unroll
    for (int c = 0; c < 5; ++c) {
      bC[2 * c]     = *(const short8*)(B1Hw + (size_t)c * 5120);
      bC[2 * c + 1] = *(const short8*)(B1Lw + (size_t)c * 5120);
    }
#pragma unroll
    for (int t = 0; t < 10; ++t) {
      // issue half1 (cf 5..9) loads for this t
#pragma unroll
      for (int c = 0; c < 5; ++c) {
        size_t off = (size_t)(5 + c) * 5120 + (size_t)t * 512;
        bN[2 * c]     = *(const short8*)(B1Hw + off);
        bN[2 * c + 1] = *(const short8*)(B1Lw + off);
      }
      if (t < 9) {
        int kk = (t + 1) * 32;
        aN[0] = *(const short8*)(pA0H + kk);
        aN[1] = *(const short8*)(pA0L + kk);
        aN[2] = *(const short8*)(pA1H + kk);
        aN[3] = *(const short8*)(pA1L + kk);
      }
      // compute half0 (cf 0..4) with bC
#pragma unroll
      for (int c = 0; c < 5; ++c) {
        acc[0][c] = MFMA(aC[0], bC[2 * c], acc[0][c], 0, 0, 0);
        acc[0][c] = MFMA(aC[0], bC[2 * c + 1], acc[0][c], 0, 0, 0);
        acc[0][c] = MFMA(aC[1], bC[2 * c], acc[0][c], 0, 0, 0);
        acc[1][c] = MFMA(aC[2], bC[2 * c], acc[1][c], 0, 0, 0);
        acc[1][c] = MFMA(aC[2], bC[2 * c + 1], acc[1][c], 0, 0, 0);
        acc[1][c] = MFMA(aC[3], bC[2 * c], acc[1][c], 0, 0, 0);
      }
      // issue half0 loads for t+1
      if (t < 9) {
#pragma unroll
        for (int c = 0; c < 5; ++c) {
          size_t off = (size_t)c * 5120 + (size_t)(t + 1) * 512;
          bC[2 * c]     = *(const short8*)(B1Hw + off);
          bC[2 * c + 1] = *(const short8*)(B1Lw + off);
        }
      }
      // compute half1 (cf 5..9) with bN
#pragma unroll
      for (int c = 0; c < 5; ++c) {
        int cf = 5 + c;
        acc[0][cf] = MFMA(aC[0], bN[2 * c], acc[0][cf], 0, 0, 0);
        acc[0][cf] = MFMA(aC[0], bN[2 * c + 1], acc[0][cf], 0, 0, 0);
        acc[0][cf] = MFMA(aC[1], bN[2 * c], acc[0][cf], 0, 0, 0);
        acc[1][cf] = MFMA(aC[2], bN[2 * c], acc[1][cf], 0, 0, 0);
        acc[1][cf] = MFMA(aC[2], bN[2 * c + 1], acc[1][cf], 0, 0, 0);
        acc[1][cf] = MFMA(aC[3], bN[2 * c], acc[1][cf], 0, 0, 0);
      }
      if (t < 9) {
        aC[0] = aN[0]; aC[1] = aN[1]; aC[2] = aN[2]; aC[3] = aN[3];
      }
    }
    // epilogue: bias+relu+split -> LDS planes
#pragma unroll
    for (int cf = 0; cf < 10; ++cf) {
      int col = w * 160 + cf * 16 + rl;
      float bv = (col < 600) ? bias1[col] : 0.f;
#pragma unroll
      for (int rt = 0; rt < 2; ++rt) {
#pragma unroll
        for (int i = 0; i < 4; ++i) {
          int row = rt * 16 + g * 4 + i;
          float v = fmaxf(acc[rt][cf][i] + bv, 0.f);
          short hi, lo;
          split_bf16(v, hi, lo);
          if (col < KP2) { iH[row][col] = hi; iL[row][col] = lo; }
        }
      }
    }
  }
  __syncthreads();
  // ================= GEMM2: pipelined (full-step double buffer) ====================
  f32x4 a2[2][5] = {};
  {
    short8 xC[4], bC[10];
    xC[0] = *(const short8*)&iH[rl][kg];
    xC[1] = *(const short8*)&iL[rl][kg];
    xC[2] = *(const short8*)&iH[16 + rl][kg];
    xC[3] = *(const short8*)&iL[16 + rl][kg];
#pragma unroll
    for (int c = 0; c < 5; ++c) {
      bC[2 * c]     = *(const short8*)(B2Hw + (size_t)c * 9728);
      bC[2 * c + 1] = *(const short8*)(B2Lw + (size_t)c * 9728);
    }
#pragma unroll
    for (int t = 0; t < 19; ++t) {
      short8 xN[4], bN[10];
      if (t < 18) {
        int kk = (t + 1) * 32 + kg;
        xN[0] = *(const short8*)&iH[rl][kk];
        xN[1] = *(const short8*)&iL[rl][kk];
        xN[2] = *(const short8*)&iH[16 + rl][kk];
        xN[3] = *(const short8*)&iL[16 + rl][kk];
#pragma unroll
        for (int c = 0; c < 5; ++c) {
          size_t off = (size_t)c * 9728 + (size_t)(t + 1) * 512;
          bN[2 * c]     = *(const short8*)(B2Hw + off);
          bN[2 * c + 1] = *(const short8*)(B2Lw + off);
        }
      }
#pragma unroll
      for (int c = 0; c < 5; ++c) {
        a2[0][c] = MFMA(xC[0], bC[2 * c], a2[0][c], 0, 0, 0);
        a2[0][c] = MFMA(xC[0], bC[2 * c + 1], a2[0][c], 0, 0, 0);
        a2[0][c] = MFMA(xC[1], bC[2 * c], a2[0][c], 0, 0, 0);
        a2[1][c] = MFMA(xC[2], bC[2 * c], a2[1][c], 0, 0, 0);
        a2[1][c] = MFMA(xC[2], bC[2 * c + 1], a2[1][c], 0, 0, 0);
        a2[1][c] = MFMA(xC[3], bC[2 * c], a2[1][c], 0, 0, 0);
      }
      if (t < 18) {
        xC[0] = xN[0]; xC[1] = xN[1]; xC[2] = xN[2]; xC[3] = xN[3];
#pragma unroll
        for (int c = 0; c < 10; ++c) bC[c] = bN[c];
      }
    }
  }
  int bk = (blockIdx.x & (NBUCK - 1)) * 600;
#pragma unroll
  for (int cf = 0; cf < 5; ++cf) {
    int col = w * 80 + cf * 16 + rl;
    float bv = (col < D) ? bias2[col] : 0.f;
    float s = 0.f, q = 0.f;
#pragma unroll
    for (int rt = 0; rt < 2; ++rt) {
#pragma unroll
      for (int i = 0; i < 4; ++i) {
        int row = r0 + rt * 16 + g * 4 + i;
        float v = a2[rt][cf][i] + bv;
        if (col < D) hout[(size_t)row * D + col] = v;
        s += v; q += v * v;
      }
    }
    s += __shfl_xor(s, 16); s += __shfl_xor(s, 32);
    q += __shfl_xor(q, 16); q += __shfl_xor(q, 32);
    if (g == 0 && col < D) {
      atomicAdd(&stats[bk + col], s);
      atomicAdd(&stats[bk + 300 + col], q);
    }
  }
}

// ---------------- fp32 tiled GEMM (projector only) ----------------
template <bool RELU>
__global__ __launch_bounds__(256) void k_gemm(const float* __restrict__ A,
                                              const float* __restrict__ Bm,
                                              const float* __restrict__ bias,
                                              float* __restrict__ C,
                                              int M, int K, int Nc) {
  __shared__ float As[8][132];
  __shared__ float Bs[8][132];
  int tid = threadIdx.x;
  int tx = tid & 15, ty = tid >> 4;
  int m0 = blockIdx.x * 128, n0 = blockIdx.y * 128;
  float acc[8][8] = {};
  int ar = tid >> 1, akq = (tid & 1) * 4;
  int bk = tid >> 5, bn = (tid & 31) * 4;
  for (int kk = 0; kk < K; kk += 8) {
    {
      int gr = m0 + ar, gk = kk + akq;
      if (gr < M && gk + 3 < K) {
        float4 v = *(const float4*)(A + (size_t)gr * K + gk);
        As[akq + 0][ar] = v.x; As[akq + 1][ar] = v.y;
        As[akq + 2][ar] = v.z; As[akq + 3][ar] = v.w;
      } else {
#pragma unroll
        for (int u = 0; u < 4; ++u)
          As[akq + u][ar] = (gr < M && gk + u < K) ? A[(size_t)gr * K + gk + u] : 0.f;
      }
    }
    {
      int gk = kk + bk, gn = n0 + bn;
      if (gk < K && gn + 3 < Nc) {
        *(float4*)&Bs[bk][bn] = *(const float4*)(Bm + (size_t)gk * Nc + gn);
      } else {
#pragma unroll
        for (int u = 0; u < 4; ++u)
          Bs[bk][bn + u] = (gk < K && gn + u < Nc) ? Bm[(size_t)gk * Nc + gn + u] : 0.f;
      }
    }
    __syncthreads();
#pragma unroll
    for (int k = 0; k < 8; ++k) {
      float4 a0 = *(const float4*)&As[k][ty * 8];
      float4 a1 = *(const float4*)&As[k][ty * 8 + 4];
      float4 b0 = *(const float4*)&Bs[k][tx * 8];
      float4 b1 = *(const float4*)&Bs[k][tx * 8 + 4];
      float av[8] = {a0.x, a0.y, a0.z, a0.w, a1.x, a1.y, a1.z, a1.w};
      float bv[8] = {b0.x, b0.y, b0.z, b0.w, b1.x, b1.y, b1.z, b1.w};
#pragma unroll
      for (int i = 0; i < 8; ++i)
#pragma unroll
        for (int j = 0; j < 8; ++j) acc[i][j] = fmaf(av[i], bv[j], acc[i][j]);
    }
    __syncthreads();
  }
  int rbase = m0 + ty * 8, cbase = n0 + tx * 8;
#pragma unroll
  for (int i = 0; i < 8; ++i) {
    int r = rbase + i;
    if (r >= M) break;
#pragma unroll
    for (int j = 0; j < 8; ++j) {
      int c = cbase + j;
      if (c >= Nc) continue;
      float v = acc[i][j] + bias[c];
      if (RELU) v = fmaxf(v, 0.f);
      C[(size_t)r * Nc + c] = v;
    }
  }
}

// ---------------- BN finalize (bucketed stats -> scale/shift) ----------------
__global__ void k_bnfinal(const float* __restrict__ stats, const float* __restrict__ g,
                          const float* __restrict__ b, float* __restrict__ scsh) {
  int t = threadIdx.x;
  if (t >= D) return;
  float s = 0.f, q = 0.f;
  for (int bk = 0; bk < NBUCK; ++bk) {
    s += stats[bk * 600 + t];
    q += stats[bk * 600 + 300 + t];
  }
  float mean = s * (1.0f / NN);
  float var = q * (1.0f / NN) - mean * mean;
  float inv = rsqrtf(var + BN_EPS_C);
  float sc = g[t] * inv;
  scsh[t] = sc;
  scsh[D + t] = b[t] - mean * sc;
}

// ---------------- pooling (batch sorted) + fused last-layer BN ----------------
__global__ void k_gstart(const int* __restrict__ batch, int* __restrict__ gs) {
  int i = blockIdx.x * blockDim.x + threadIdx.x;
  if (i >= NN) return;
  int b = batch[i];
  int bp = (i == 0) ? -1 : batch[i - 1];
  for (int q = bp + 1; q <= b; ++q) gs[q] = i;
  if (i == NN - 1)
    for (int q = b + 1; q <= NB; ++q) gs[q] = NN;
}

__global__ void k_poolseg(const float* __restrict__ h, const int* __restrict__ gs,
                          const float* __restrict__ scsh, float* __restrict__ g) {
  int b = blockIdx.x;
  int j0 = gs[b], j1 = gs[b + 1];
  int t = threadIdx.x;               // 128
  float s0 = 0, s1 = 0, s2 = 0;
  int c2 = t + 256;
  for (int j = j0; j < j1; ++j) {
    const float* row = h + (size_t)j * D;
    s0 += row[t];
    s1 += row[t + 128];
    if (c2 < D) s2 += row[c2];
  }
  bool nz = j1 > j0;
  float invc = nz ? 1.f / (float)(j1 - j0) : 0.f;
  float* go = g + (size_t)b * D;
  go[t] = nz ? fmaf(s0 * invc, scsh[t], scsh[D + t]) : 0.f;
  go[t + 128] = nz ? fmaf(s1 * invc, scsh[t + 128], scsh[D + t + 128]) : 0.f;
  if (c2 < D) go[c2] = nz ? fmaf(s2 * invc, scsh[c2], scsh[D + c2]) : 0.f;
}

// ---------------- L2 normalize -> split feature planes [4096, FKP] ----------------
__global__ void k_norm(const float* __restrict__ pin, short* __restrict__ FH,
                       short* __restrict__ FL, int ro) {
  int b = blockIdx.x;
  int t = threadIdx.x;               // 64
  const float* row = pin + (size_t)b * D;
  float q = 0;
  for (int c = t; c < D; c += 64) { float v = row[c]; q += v * v; }
#pragma unroll
  for (int off = 32; off > 0; off >>= 1) q += __shfl_down(q, off);
  q = __shfl(q, 0);
  float inv = 1.f / fmaxf(sqrtf(q), 1e-12f);
  size_t base = (size_t)(ro + b) * FKP;
  for (int c = t; c < FKP; c += 64) {
    float v = (c < D) ? row[c] * inv : 0.f;
    short hi, lo;
    split_bf16(v, hi, lo);
    FH[base + c] = hi;
    FL[base + c] = lo;
  }
}

// ---------------- MFMA sim = F F^T fused with NT-Xent logits layout ----------------
__global__ __launch_bounds__(256) void k_logits_mfma(const short* __restrict__ FH,
                                                     const short* __restrict__ FL,
                                                     float* __restrict__ out) {
  int lane = threadIdx.x & 63;
  int w = threadIdx.x >> 6;
  int m0 = blockIdx.x * 128 + (w >> 1) * 64;
  int n0 = blockIdx.y * 128 + (w & 1) * 64;
  int rl = lane & 15;
  int kg = (lane >> 4) * 8;
  f32x4 acc[4][4] = {};
  for (int k0 = 0; k0 < FKP; k0 += 32) {
    int kk = k0 + kg;
    short8 aH[4], aL[4], bH[4], bL[4];
#pragma unroll
    for (int rf = 0; rf < 4; ++rf) {
      size_t off = (size_t)(m0 + rf * 16 + rl) * FKP + kk;
      aH[rf] = *(const short8*)(FH + off);
      aL[rf] = *(const short8*)(FL + off);
    }
#pragma unroll
    for (int cf = 0; cf < 4; ++cf) {
      size_t off = (size_t)(n0 + cf * 16 + rl) * FKP + kk;
      bH[cf] = *(const short8*)(FH + off);
      bL[cf] = *(const short8*)(FL + off);
    }
#pragma unroll
    for (int rf = 0; rf < 4; ++rf)
#pragma unroll
      for (int cf = 0; cf < 4; ++cf) {
        acc[rf][cf] = MFMA(aH[rf], bH[cf], acc[rf][cf], 0, 0, 0);
        acc[rf][cf] = MFMA(aH[rf], bL[cf], acc[rf][cf], 0, 0, 0);
        acc[rf][cf] = MFMA(aL[rf], bH[cf], acc[rf][cf], 0, 0, 0);
      }
  }
#pragma unroll
  for (int rf = 0; rf < 4; ++rf) {
#pragma unroll
    for (int cf = 0; cf < 4; ++cf) {
      int c = n0 + cf * 16 + rl;
#pragma unroll
      for (int i = 0; i < 4; ++i) {
        int r = m0 + rf * 16 + (lane >> 4) * 4 + i;
        if (c == r) continue;
        float v = acc[rf][cf][i] * TEMP_INV;
        int posj = (r + NB) & 4095;
        int slot = (c == posj) ? 0 : (1 + c - (c > r) - (c > posj));
        out[(size_t)r * 4095 + slot] = v;
      }
    }
  }
}

// ---------------- host ----------------
extern "C" void kernel_launch(void* const* d_in, const int* in_sizes, int n_in,
                              void* d_out, int out_size, void* d_ws, size_t ws_size,
                              hipStream_t stream) {
  const int* xs[2] = {(const int*)d_in[0], (const int*)d_in[4]};
  const int* eis[2] = {(const int*)d_in[1], (const int*)d_in[5]};
  const int* eas[2] = {(const int*)d_in[2], (const int*)d_in[6]};
  const int* bts[2] = {(const int*)d_in[3], (const int*)d_in[7]};
  const float* ae1 = (const float*)d_in[8];
  const float* ae2 = (const float*)d_in[9];
  const float* ee1 = (const float*)d_in[10];
  const float* ee2 = (const float*)d_in[11];
  const float* W1 = (const float*)d_in[12];
  const float* b1 = (const float*)d_in[13];
  const float* W2 = (const float*)d_in[14];
  const float* b2 = (const float*)d_in[15];
  const float* bng = (const float*)d_in[16];
  const float* bnb = (const float*)d_in[17];
  const float* pW1 = (const float*)d_in[18];
  const float* pb1 = (const float*)d_in[19];
  const float* pW2 = (const float*)d_in[20];
  const float* pb2 = (const float*)d_in[21];

  char* p = (char*)d_ws;
  auto alloc = [&](size_t bytes) -> void* {
    void* q = (void*)p;
    p += (bytes + 255) & ~(size_t)255;
    return q;
  };
  float* h    = (float*)alloc((size_t)NN * D * 4);          // 98.3 MB
  short* aggH = (short*)alloc((size_t)NN * KP1 * 2);        // 52.4 MB
  short* aggL = (short*)alloc((size_t)NN * KP1 * 2);        // 52.4 MB
  short* w1tH = (short*)alloc((size_t)NL * P1FR * 2);       // 2.05 MB
  short* w1tL = (short*)alloc((size_t)NL * P1FR * 2);
  short* w2tH = (short*)alloc((size_t)NL * P2FR * 2);       // 1.95 MB
  short* w2tL = (short*)alloc((size_t)NL * P2FR * 2);
  short* featH = (short*)alloc((size_t)2 * NB * FKP * 2);
  short* featL = (short*)alloc((size_t)2 * NB * FKP * 2);
  int* cnt    = (int*)alloc((size_t)NN * 4);
  int* rs     = (int*)alloc((size_t)(NN + 1) * 4);
  int* srcs   = (int*)alloc((size_t)NE * 4);
  int* attrs  = (int*)alloc((size_t)NE * 4);
  float* stats = (float*)alloc((size_t)NBUCK * 600 * 4);    // 153.6 KB
  float* scsh  = (float*)alloc(600 * 4);
  int* gstart  = (int*)alloc((size_t)(NB + 1) * 4);
  float* pg   = (float*)alloc((size_t)NB * D * 4);
  float* pt   = (float*)alloc((size_t)NB * D * 4);
  // total ~ 227 MB

  k_prepw1<<<(NL * P1FR + 255) / 256, 256, 0, stream>>>(W1, w1tH, w1tL);
  k_prepw2<<<(NL * P2FR + 255) / 256, 256, 0, stream>>>(W2, w2tH, w2tL);

  for (int v = 0; v < 2; ++v) {
    k_init_h<<<NN, 128, 0, stream>>>(xs[v], ae1, ae2, h);
    hipMemsetAsync(cnt, 0, (size_t)NN * 4, stream);
    k_count<<<(NE + 255) / 256, 256, 0, stream>>>(eis[v], cnt);
    k_scan<<<1, 1024, 0, stream>>>(cnt, rs);
    hipMemsetAsync(cnt, 0, (size_t)NN * 4, stream);
    k_bucket<<<(NE + 255) / 256, 256, 0, stream>>>(eis[v], eas[v], rs, cnt, srcs, attrs);

    for (int l = 0; l < NL; ++l) {
      if (l == 0)
        k_gather<false><<<NN, 128, 0, stream>>>(h, rs, srcs, attrs, ee1 + (size_t)l * 6 * D,
                                                ee2 + (size_t)l * 3 * D, nullptr, aggH, aggL);
      else
        k_gather<true><<<NN, 128, 0, stream>>>(h, rs, srcs, attrs, ee1 + (size_t)l * 6 * D,
                                               ee2 + (size_t)l * 3 * D, scsh, aggH, aggL);
      hipMemsetAsync(stats, 0, (size_t)NBUCK * 600 * 4, stream);
      k_mlp<<<NN / 32, 256, 0, stream>>>(
          aggH, aggL,
          w1tH + (size_t)l * P1FR, w1tL + (size_t)l * P1FR,
          w2tH + (size_t)l * P2FR, w2tL + (size_t)l * P2FR,
          b1 + (size_t)l * 600, b2 + (size_t)l * 300, h, stats);
      k_bnfinal<<<1, 320, 0, stream>>>(stats, bng + (size_t)l * D, bnb + (size_t)l * D, scsh);
    }

    k_gstart<<<(NN + 255) / 256, 256, 0, stream>>>(bts[v], gstart);
    k_poolseg<<<NB, 128, 0, stream>>>(h, gstart, scsh, pg);
    k_gemm<true><<<dim3(NB / 128, (D + 127) / 128), 256, 0, stream>>>(pg, pW1, pb1, pt, NB, D, D);
    k_gemm<false><<<dim3(NB / 128, (D + 127) / 128), 256, 0, stream>>>(pt, pW2, pb2, pg, NB, D, D);
    k_norm<<<NB, 64, 0, stream>>>(pg, featH, featL, v * NB);
  }

  k_logits_mfma<<<dim3(4096 / 128, 4096 / 128), 256, 0, stream>>>(featH, featL, (float*)d_out);
  hipMemsetAsync((float*)d_out + (size_t)4096 * 4095, 0, (size_t)4096 * 4, stream);
}